// Round 1
// baseline (2967.531 us; speedup 1.0000x reference)
//
#include <hip/hip_runtime.h>

#define BB 2
#define NN 4096
#define CC 256
#define FF 1024
#define NLAYER 4
#define RR (BB*NN)
#define SPLITA 4
#define SPLITB 4
#define NEG_BIG (-1e30f)

// ---------------- embed: [B,N,3] @ [3,256] + b ----------------
__global__ __launch_bounds__(256) void pct_embed(const float* __restrict__ inp,
    const float* __restrict__ w0, const float* __restrict__ b0, float* __restrict__ out)
{
    int r = blockIdx.x, c = threadIdx.x;
    float a0 = inp[r*3+0], a1 = inp[r*3+1], a2 = inp[r*3+2];
    out[(size_t)r*CC + c] = b0[c] + a0*w0[c] + a1*w0[CC+c] + a2*w0[2*CC+c];
}

// ---------------- column stats over points axis (per batch, per channel) ----------------
__global__ __launch_bounds__(256) void pct_colstat(const float* __restrict__ x, int ldx,
    float* __restrict__ sums)
{
    int b = blockIdx.x, blk = blockIdx.y;       // gridDim.y = 64 -> 64 rows each
    const int rows = NN / 64;
    int c = threadIdx.x;
    const float* p = x + ((size_t)b*NN + (size_t)blk*rows)*ldx + c;
    float s1 = 0.f, s2 = 0.f;
    for (int i = 0; i < rows; ++i) { float v = p[(size_t)i*ldx]; s1 += v; s2 += v*v; }
    atomicAdd(&sums[(b*CC + c)*2 + 0], s1);
    atomicAdd(&sums[(b*CC + c)*2 + 1], s2);
}

// ---------------- apply LN (stats over points), optional relu + residual ----------------
__global__ __launch_bounds__(256) void pct_lnapply(const float* __restrict__ x, int ldx,
    const float* __restrict__ sums, const float* __restrict__ scale, const float* __restrict__ bias,
    const float* __restrict__ res, int ldr, float* __restrict__ out, int ldo, int do_relu)
{
    int r = blockIdx.x, c = threadIdx.x;
    int b = r / NN;
    float s1 = sums[(b*CC + c)*2], s2 = sums[(b*CC + c)*2 + 1];
    float mu  = s1 * (1.f/NN);
    float var = s2 * (1.f/NN) - mu*mu;
    float rstd = rsqrtf(var + 1e-6f);
    float y = (x[(size_t)r*ldx + c] - mu) * rstd * scale[c] + bias[c];
    if (do_relu) y = fmaxf(y, 0.f);
    if (res) y += res[(size_t)r*ldr + c];
    out[(size_t)r*ldo + c] = y;
}

// ---------------- generic f32 tiled GEMM: out[r,j] = bias[j] + sum_k A[r,k]*W[k,j] ----------------
__global__ __launch_bounds__(256) void pct_gemm(const float* __restrict__ A, int lda,
    const float* __restrict__ W, int ldw, const float* __restrict__ bias,
    float* __restrict__ out, int ldo, int K)
{
    __shared__ float As[16][68];
    __shared__ float Ws[16][68];
    int tid = threadIdx.x;
    int tx = tid & 15, ty = tid >> 4;
    int r0 = blockIdx.x * 64, j0 = blockIdx.y * 64;
    float acc[4][4] = {};
    for (int k0 = 0; k0 < K; k0 += 16) {
        int ar = tid >> 4, ak = tid & 15;
        #pragma unroll
        for (int it = 0; it < 4; ++it)
            As[ak][ar + it*16] = A[(size_t)(r0 + ar + it*16)*lda + k0 + ak];
        int wj = tid & 63, wk = tid >> 6;   // wk 0..3
        #pragma unroll
        for (int it = 0; it < 4; ++it)
            Ws[wk + it*4][wj] = W[(size_t)(k0 + wk + it*4)*ldw + j0 + wj];
        __syncthreads();
        #pragma unroll
        for (int kk = 0; kk < 16; ++kk) {
            float a[4], w[4];
            #pragma unroll
            for (int i = 0; i < 4; ++i) a[i] = As[kk][ty*4 + i];
            #pragma unroll
            for (int j = 0; j < 4; ++j) w[j] = Ws[kk][tx*4 + j];
            #pragma unroll
            for (int i = 0; i < 4; ++i)
                #pragma unroll
                for (int j = 0; j < 4; ++j) acc[i][j] += a[i]*w[j];
        }
        __syncthreads();
    }
    #pragma unroll
    for (int i = 0; i < 4; ++i) {
        int r = r0 + ty*4 + i;
        #pragma unroll
        for (int j = 0; j < 4; ++j) {
            int jj = j0 + tx*4 + j;
            out[(size_t)r*ldo + jj] = acc[i][j] + bias[jj];
        }
    }
}

// ---------------- pass A: row max / row sumexp of Q@K^T (online, split over n) ----------------
__global__ __launch_bounds__(256) void pct_rowstats(const float* __restrict__ Q,
    const float* __restrict__ Km, float* __restrict__ part)
{
    int b = blockIdx.x, mt = blockIdx.y, sp = blockIdx.z;
    __shared__ float As[16][68], Ws[16][68];
    __shared__ float redm[64][17], reds[64][17];
    int tid = threadIdx.x, tx = tid & 15, ty = tid >> 4;
    const float* qb = Q + (size_t)b*NN*CC;
    const float* kb = Km + (size_t)b*NN*CC;
    int m0 = mt * 64;
    float rm[4], rs[4];
    #pragma unroll
    for (int i = 0; i < 4; ++i) { rm[i] = NEG_BIG; rs[i] = 0.f; }
    int n_begin = sp * (NN/SPLITA), n_end = n_begin + NN/SPLITA;
    for (int n0 = n_begin; n0 < n_end; n0 += 64) {
        float acc[4][4] = {};
        for (int k0 = 0; k0 < CC; k0 += 16) {
            int ar = tid >> 4, ak = tid & 15;
            #pragma unroll
            for (int it = 0; it < 4; ++it)
                As[ak][ar + it*16] = qb[(size_t)(m0 + ar + it*16)*CC + k0 + ak];
            #pragma unroll
            for (int it = 0; it < 4; ++it)
                Ws[ak][ar + it*16] = kb[(size_t)(n0 + ar + it*16)*CC + k0 + ak];
            __syncthreads();
            #pragma unroll
            for (int kk = 0; kk < 16; ++kk) {
                float a[4], w[4];
                #pragma unroll
                for (int i = 0; i < 4; ++i) a[i] = As[kk][ty*4 + i];
                #pragma unroll
                for (int j = 0; j < 4; ++j) w[j] = Ws[kk][tx*4 + j];
                #pragma unroll
                for (int i = 0; i < 4; ++i)
                    #pragma unroll
                    for (int j = 0; j < 4; ++j) acc[i][j] += a[i]*w[j];
            }
            __syncthreads();
        }
        #pragma unroll
        for (int i = 0; i < 4; ++i) {
            float tm = fmaxf(fmaxf(acc[i][0], acc[i][1]), fmaxf(acc[i][2], acc[i][3]));
            if (tm > rm[i]) { rs[i] *= __expf(rm[i] - tm); rm[i] = tm; }
            #pragma unroll
            for (int j = 0; j < 4; ++j) rs[i] += __expf(acc[i][j] - rm[i]);
        }
    }
    #pragma unroll
    for (int i = 0; i < 4; ++i) { redm[ty*4+i][tx] = rm[i]; reds[ty*4+i][tx] = rs[i]; }
    __syncthreads();
    if (tid < 64) {
        int row = tid;
        float m = NEG_BIG;
        for (int t = 0; t < 16; ++t) m = fmaxf(m, redm[row][t]);
        float s = 0.f;
        for (int t = 0; t < 16; ++t) s += reds[row][t] * __expf(redm[row][t] - m);
        size_t idx = (((size_t)b*NN + m0 + row)*SPLITA + sp)*2;
        part[idx] = m; part[idx+1] = s;
    }
}

// ---------------- combine split row stats; store (rmax, 1/rsum) ----------------
__global__ __launch_bounds__(256) void pct_rowcomb(const float* __restrict__ part,
    float* __restrict__ rstat)
{
    int idx = blockIdx.x*256 + threadIdx.x;   // global row 0..RR-1
    const float* p = part + (size_t)idx*SPLITA*2;
    float m = NEG_BIG;
    for (int s = 0; s < SPLITA; ++s) m = fmaxf(m, p[s*2]);
    float sum = 0.f;
    for (int s = 0; s < SPLITA; ++s) sum += p[s*2+1] * __expf(p[s*2] - m);
    rstat[idx*2] = m; rstat[idx*2+1] = 1.0f / sum;
}

// ---------------- pass B: column sums of softmax(Q@K^T) (recompute, split over m) ----------------
__global__ __launch_bounds__(256) void pct_colsum(const float* __restrict__ Q,
    const float* __restrict__ Km, const float* __restrict__ rstat, float* __restrict__ S)
{
    int b = blockIdx.x, nt = blockIdx.y, sp = blockIdx.z;
    __shared__ float As[16][68], Ws[16][68];
    __shared__ float redc[64][17];
    int tid = threadIdx.x, tx = tid & 15, ty = tid >> 4;
    const float* qb = Q + (size_t)b*NN*CC;
    const float* kb = Km + (size_t)b*NN*CC;
    int n0 = nt * 64;
    float sc[4] = {0.f, 0.f, 0.f, 0.f};
    int m_begin = sp * (NN/SPLITB), m_end = m_begin + NN/SPLITB;
    for (int m0 = m_begin; m0 < m_end; m0 += 64) {
        float acc[4][4] = {};
        for (int k0 = 0; k0 < CC; k0 += 16) {
            int ar = tid >> 4, ak = tid & 15;
            #pragma unroll
            for (int it = 0; it < 4; ++it)
                As[ak][ar + it*16] = qb[(size_t)(m0 + ar + it*16)*CC + k0 + ak];
            #pragma unroll
            for (int it = 0; it < 4; ++it)
                Ws[ak][ar + it*16] = kb[(size_t)(n0 + ar + it*16)*CC + k0 + ak];
            __syncthreads();
            #pragma unroll
            for (int kk = 0; kk < 16; ++kk) {
                float a[4], w[4];
                #pragma unroll
                for (int i = 0; i < 4; ++i) a[i] = As[kk][ty*4 + i];
                #pragma unroll
                for (int j = 0; j < 4; ++j) w[j] = Ws[kk][tx*4 + j];
                #pragma unroll
                for (int i = 0; i < 4; ++i)
                    #pragma unroll
                    for (int j = 0; j < 4; ++j) acc[i][j] += a[i]*w[j];
            }
            __syncthreads();
        }
        #pragma unroll
        for (int i = 0; i < 4; ++i) {
            size_t ri = ((size_t)b*NN + m0 + ty*4 + i)*2;
            float rmax = rstat[ri], inv = rstat[ri+1];
            #pragma unroll
            for (int j = 0; j < 4; ++j) sc[j] += __expf(acc[i][j] - rmax) * inv;
        }
    }
    #pragma unroll
    for (int j = 0; j < 4; ++j) redc[tx*4+j][ty] = sc[j];
    __syncthreads();
    if (tid < 64) {
        int col = tid;
        float s = 0.f;
        for (int t = 0; t < 16; ++t) s += redc[col][t];
        atomicAdd(&S[(size_t)b*NN + n0 + col], s);
    }
}

// ---------------- scale v rows by col = S/(eps+S) ----------------
__global__ __launch_bounds__(256) void pct_vscale(float* __restrict__ v, const float* __restrict__ S)
{
    int r = blockIdx.x, c = threadIdx.x;
    float s = S[r];
    float f = s / (1e-9f + s);
    v[(size_t)r*CC + c] *= f;
}

extern "C" void kernel_launch(void* const* d_in, const int* in_sizes, int n_in,
                              void* d_out, int out_size, void* d_ws, size_t ws_size,
                              hipStream_t stream)
{
    const float* inp  = (const float*)d_in[0];
    const float* w0   = (const float*)d_in[1];
    const float* b0   = (const float*)d_in[2];
    const float* ln0s = (const float*)d_in[3];
    const float* ln0b = (const float*)d_in[4];
    const float* w1   = (const float*)d_in[5];
    const float* b1   = (const float*)d_in[6];
    const float* ln1s = (const float*)d_in[7];
    const float* ln1b = (const float*)d_in[8];
    const float* wq   = (const float*)d_in[9];
    const float* bq   = (const float*)d_in[10];
    const float* wk   = (const float*)d_in[11];
    const float* bk   = (const float*)d_in[12];
    const float* wv   = (const float*)d_in[13];
    const float* bv   = (const float*)d_in[14];
    const float* wo   = (const float*)d_in[15];
    const float* bo   = (const float*)d_in[16];
    const float* alns = (const float*)d_in[17];
    const float* alnb = (const float*)d_in[18];
    const float* wf   = (const float*)d_in[19];
    const float* bfb  = (const float*)d_in[20];
    float* out = (float*)d_out;

    float* ws = (float*)d_ws;
    float* x1    = ws;
    float* xcat  = x1 + (size_t)RR*CC;
    float* qb    = xcat + (size_t)RR*FF;
    float* kb    = qb + (size_t)RR*CC;
    float* vb    = kb + (size_t)RR*CC;
    float* part  = vb + (size_t)RR*CC;
    float* rstat = part + (size_t)RR*SPLITA*2;
    float* Ssum  = rstat + (size_t)RR*2;
    float* lns   = Ssum + RR;

    dim3 blk(256);

    // pre-conv stack
    pct_embed<<<RR, blk, 0, stream>>>(inp, w0, b0, kb);
    hipMemsetAsync(lns, 0, BB*CC*2*sizeof(float), stream);
    pct_colstat<<<dim3(BB,64), blk, 0, stream>>>(kb, CC, lns);
    pct_lnapply<<<RR, blk, 0, stream>>>(kb, CC, lns, ln0s, ln0b, nullptr, 0, vb, CC, 0);
    pct_gemm<<<dim3(RR/64, CC/64), blk, 0, stream>>>(vb, CC, w1, CC, b1, qb, CC, CC);
    hipMemsetAsync(lns, 0, BB*CC*2*sizeof(float), stream);
    pct_colstat<<<dim3(BB,64), blk, 0, stream>>>(qb, CC, lns);
    pct_lnapply<<<RR, blk, 0, stream>>>(qb, CC, lns, ln1s, ln1b, nullptr, 0, x1, CC, 0);

    const float* xin = x1; int ldx = CC;
    for (int i = 0; i < NLAYER; ++i) {
        const float* wqi = wq + (size_t)i*CC*CC; const float* bqi = bq + i*CC;
        const float* wki = wk + (size_t)i*CC*CC; const float* bki = bk + i*CC;
        const float* wvi = wv + (size_t)i*CC*CC; const float* bvi = bv + i*CC;
        const float* woi = wo + (size_t)i*CC*CC; const float* boi = bo + i*CC;

        pct_gemm<<<dim3(RR/64, CC/64), blk, 0, stream>>>(xin, ldx, wqi, CC, bqi, qb, CC, CC);
        pct_gemm<<<dim3(RR/64, CC/64), blk, 0, stream>>>(xin, ldx, wki, CC, bki, kb, CC, CC);
        pct_gemm<<<dim3(RR/64, CC/64), blk, 0, stream>>>(xin, ldx, wvi, CC, bvi, vb, CC, CC);

        pct_rowstats<<<dim3(BB, NN/64, SPLITA), blk, 0, stream>>>(qb, kb, part);
        pct_rowcomb<<<RR/256, blk, 0, stream>>>(part, rstat);
        hipMemsetAsync(Ssum, 0, RR*sizeof(float), stream);
        pct_colsum<<<dim3(BB, NN/64, SPLITB), blk, 0, stream>>>(qb, kb, rstat, Ssum);

        pct_vscale<<<RR, blk, 0, stream>>>(vb, Ssum);
        pct_gemm<<<dim3(RR/64, CC/64), blk, 0, stream>>>(vb, CC, woi, CC, boi, qb, CC, CC);

        hipMemsetAsync(lns, 0, BB*CC*2*sizeof(float), stream);
        pct_colstat<<<dim3(BB,64), blk, 0, stream>>>(qb, CC, lns);
        pct_lnapply<<<RR, blk, 0, stream>>>(qb, CC, lns, alns + i*CC, alnb + i*CC,
                                            xin, ldx, xcat + i*CC, FF, 1);
        xin = xcat + i*CC; ldx = FF;
    }

    pct_gemm<<<dim3(RR/64, FF/64), blk, 0, stream>>>(xcat, FF, wf, FF, bfb, out, FF, FF);
}

// Round 2
// 1180.557 us; speedup vs baseline: 2.5137x; 2.5137x over previous
//
#include <hip/hip_runtime.h>
#include <hip/hip_bf16.h>

#define BB 2
#define NN 4096
#define CC 256
#define FF 1024
#define NLAYER 4
#define RR (BB*NN)
#define SPLITA 8
#define SPLITB 8
#define NEG_BIG (-1e30f)

typedef __attribute__((ext_vector_type(8))) short short8;
typedef __attribute__((ext_vector_type(4))) float f32x4;

// ---------------- async global->LDS, 16B per lane ----------------
__device__ __forceinline__ void gload16(const __hip_bfloat16* g, __hip_bfloat16* l) {
    __builtin_amdgcn_global_load_lds((const __attribute__((address_space(1))) void*)g,
                                     (__attribute__((address_space(3))) void*)l, 16, 0, 0);
}

// stage a 128x64 bf16 chunk (global rows row0..row0+127, k-cols c0..c0+63, ld=CC)
// into lds[128][64] with piece-XOR swizzle (phys piece pp holds logical piece pp^(row&7))
__device__ __forceinline__ void stage_chunk(const __hip_bfloat16* __restrict__ src,
    int row0, int c0, __hip_bfloat16* lds, int tid)
{
    int w = tid >> 6;
    #pragma unroll
    for (int t = 0; t < 4; ++t) {
        int slot = t*256 + tid;
        int row = slot >> 3;
        int pp  = slot & 7;
        int piece = pp ^ (row & 7);
        gload16(src + (size_t)(row0 + row)*CC + c0 + piece*8,
                lds + (t*256 + w*64)*8);
    }
}

// read 8 contiguous bf16 (logical k-piece pl) of LDS row
__device__ __forceinline__ short8 frag_ld(const __hip_bfloat16* lds, int row, int pl) {
    return *(const short8*)(lds + row*64 + ((pl ^ (row & 7))*8));
}

// one K=64 chunk of the 128x128 MFMA tile: 2 k-steps x 4x4 16x16x32 MFMAs/wave
__device__ __forceinline__ void mfma_chunk(const __hip_bfloat16* Asm, const __hip_bfloat16* Bsm,
    int wr, int wc, int ln, int lq, f32x4 acc[4][4])
{
    #pragma unroll
    for (int kk = 0; kk < 2; ++kk) {
        short8 af[4], bfr[4];
        #pragma unroll
        for (int i = 0; i < 4; ++i) af[i] = frag_ld(Asm, wr*64 + i*16 + ln, kk*4 + lq);
        #pragma unroll
        for (int j = 0; j < 4; ++j) bfr[j] = frag_ld(Bsm, wc*64 + j*16 + ln, kk*4 + lq);
        #pragma unroll
        for (int i = 0; i < 4; ++i)
            #pragma unroll
            for (int j = 0; j < 4; ++j)
                acc[i][j] = __builtin_amdgcn_mfma_f32_16x16x32_bf16(af[i], bfr[j], acc[i][j], 0, 0, 0);
    }
}

// ---------------- embed: [B,N,3] @ [3,256] + b ----------------
__global__ __launch_bounds__(256) void pct_embed(const float* __restrict__ inp,
    const float* __restrict__ w0, const float* __restrict__ b0, float* __restrict__ out)
{
    int r = blockIdx.x, c = threadIdx.x;
    float a0 = inp[r*3+0], a1 = inp[r*3+1], a2 = inp[r*3+2];
    out[(size_t)r*CC + c] = b0[c] + a0*w0[c] + a1*w0[CC+c] + a2*w0[2*CC+c];
}

// ---------------- column stats over points axis ----------------
__global__ __launch_bounds__(256) void pct_colstat(const float* __restrict__ x, int ldx,
    float* __restrict__ sums)
{
    int b = blockIdx.x, blk = blockIdx.y;
    const int rows = NN / 64;
    int c = threadIdx.x;
    const float* p = x + ((size_t)b*NN + (size_t)blk*rows)*ldx + c;
    float s1 = 0.f, s2 = 0.f;
    for (int i = 0; i < rows; ++i) { float v = p[(size_t)i*ldx]; s1 += v; s2 += v*v; }
    atomicAdd(&sums[(b*CC + c)*2 + 0], s1);
    atomicAdd(&sums[(b*CC + c)*2 + 1], s2);
}

// ---------------- apply LN (stats over points), optional relu + residual ----------------
__global__ __launch_bounds__(256) void pct_lnapply(const float* __restrict__ x, int ldx,
    const float* __restrict__ sums, const float* __restrict__ scale, const float* __restrict__ bias,
    const float* __restrict__ res, int ldr, float* __restrict__ out, int ldo, int do_relu)
{
    int r = blockIdx.x, c = threadIdx.x;
    int b = r / NN;
    float s1 = sums[(b*CC + c)*2], s2 = sums[(b*CC + c)*2 + 1];
    float mu  = s1 * (1.f/NN);
    float var = s2 * (1.f/NN) - mu*mu;
    float rstd = rsqrtf(var + 1e-6f);
    float y = (x[(size_t)r*ldx + c] - mu) * rstd * scale[c] + bias[c];
    if (do_relu) y = fmaxf(y, 0.f);
    if (res) y += res[(size_t)r*ldr + c];
    out[(size_t)r*ldo + c] = y;
}

// ---------------- generic f32 tiled GEMM (non-attention paths) ----------------
__global__ __launch_bounds__(256) void pct_gemm(const float* __restrict__ A, int lda,
    const float* __restrict__ W, int ldw, const float* __restrict__ bias,
    float* __restrict__ out, int ldo, int K)
{
    __shared__ float As[16][68];
    __shared__ float Ws[16][68];
    int tid = threadIdx.x;
    int tx = tid & 15, ty = tid >> 4;
    int r0 = blockIdx.x * 64, j0 = blockIdx.y * 64;
    float acc[4][4] = {};
    for (int k0 = 0; k0 < K; k0 += 16) {
        int ar = tid >> 4, ak = tid & 15;
        #pragma unroll
        for (int it = 0; it < 4; ++it)
            As[ak][ar + it*16] = A[(size_t)(r0 + ar + it*16)*lda + k0 + ak];
        int wj = tid & 63, wk = tid >> 6;
        #pragma unroll
        for (int it = 0; it < 4; ++it)
            Ws[wk + it*4][wj] = W[(size_t)(k0 + wk + it*4)*ldw + j0 + wj];
        __syncthreads();
        #pragma unroll
        for (int kk = 0; kk < 16; ++kk) {
            float a[4], w[4];
            #pragma unroll
            for (int i = 0; i < 4; ++i) a[i] = As[kk][ty*4 + i];
            #pragma unroll
            for (int j = 0; j < 4; ++j) w[j] = Ws[kk][tx*4 + j];
            #pragma unroll
            for (int i = 0; i < 4; ++i)
                #pragma unroll
                for (int j = 0; j < 4; ++j) acc[i][j] += a[i]*w[j];
        }
        __syncthreads();
    }
    #pragma unroll
    for (int i = 0; i < 4; ++i) {
        int r = r0 + ty*4 + i;
        #pragma unroll
        for (int j = 0; j < 4; ++j) {
            int jj = j0 + tx*4 + j;
            out[(size_t)r*ldo + jj] = acc[i][j] + bias[jj];
        }
    }
}

// ---------------- f32 -> bf16 convert (4 per thread) ----------------
__global__ __launch_bounds__(256) void pct_tobf16(const float* __restrict__ x,
    __hip_bfloat16* __restrict__ y)
{
    int i = (blockIdx.x*256 + threadIdx.x)*4;
    float4 v = *(const float4*)(x + i);
    union { __hip_bfloat16 h[4]; ushort4 u; } o;
    o.h[0] = __float2bfloat16(v.x); o.h[1] = __float2bfloat16(v.y);
    o.h[2] = __float2bfloat16(v.z); o.h[3] = __float2bfloat16(v.w);
    *(ushort4*)(y + i) = o.u;
}

// ---------------- pass A: row max/sumexp of Q@K^T via MFMA ----------------
__global__ __launch_bounds__(256) void pct_rowstats_mfma(
    const __hip_bfloat16* __restrict__ Q, const __hip_bfloat16* __restrict__ Kb,
    float* __restrict__ part)
{
    __shared__ __align__(16) __hip_bfloat16 Asm[128*64];
    __shared__ __align__(16) __hip_bfloat16 Bsm[128*64];
    const int b = blockIdx.x, mt = blockIdx.y, sp = blockIdx.z;
    const int tid = threadIdx.x;
    const int lane = tid & 63, w = tid >> 6;
    const int ln = lane & 15, lq = lane >> 4;
    const int wr = w >> 1, wc = w & 1;
    const __hip_bfloat16* qb = Q + (size_t)b*NN*CC;
    const __hip_bfloat16* kb = Kb + (size_t)b*NN*CC;
    const int m0 = mt*128;
    float rm[4][4], rs[4][4];
    #pragma unroll
    for (int i = 0; i < 4; ++i)
        #pragma unroll
        for (int r = 0; r < 4; ++r) { rm[i][r] = NEG_BIG; rs[i][r] = 0.f; }

    const int nbeg = sp*(NN/SPLITA);
    for (int n0 = nbeg; n0 < nbeg + NN/SPLITA; n0 += 128) {
        f32x4 acc[4][4];
        #pragma unroll
        for (int i = 0; i < 4; ++i)
            #pragma unroll
            for (int j = 0; j < 4; ++j) acc[i][j] = (f32x4){0.f,0.f,0.f,0.f};
        for (int c = 0; c < 4; ++c) {
            stage_chunk(qb, m0, c*64, Asm, tid);
            stage_chunk(kb, n0, c*64, Bsm, tid);
            __syncthreads();
            mfma_chunk(Asm, Bsm, wr, wc, ln, lq, acc);
            __syncthreads();
        }
        // per-lane online update over this tile's 4 cols per row (no shuffles here)
        #pragma unroll
        for (int i = 0; i < 4; ++i)
            #pragma unroll
            for (int r = 0; r < 4; ++r) {
                float a0 = acc[i][0][r], a1 = acc[i][1][r], a2 = acc[i][2][r], a3 = acc[i][3][r];
                float tm = fmaxf(fmaxf(a0,a1), fmaxf(a2,a3));
                float m = rm[i][r];
                if (tm > m) { rs[i][r] *= __expf(m - tm); m = tm; rm[i][r] = tm; }
                rs[i][r] += __expf(a0-m) + __expf(a1-m) + __expf(a2-m) + __expf(a3-m);
            }
    }
    // combine the 16 lanes of each row group once
    #pragma unroll
    for (int i = 0; i < 4; ++i)
        #pragma unroll
        for (int r = 0; r < 4; ++r) {
            float m = rm[i][r], s = rs[i][r];
            #pragma unroll
            for (int msk = 1; msk <= 8; msk <<= 1) {
                float mo = __shfl_xor(m, msk, 64);
                float so = __shfl_xor(s, msk, 64);
                float mn = fmaxf(m, mo);
                s = s*__expf(m-mn) + so*__expf(mo-mn);
                m = mn;
            }
            rm[i][r] = m; rs[i][r] = s;
        }
    if (ln == 0) {
        #pragma unroll
        for (int i = 0; i < 4; ++i)
            #pragma unroll
            for (int r = 0; r < 4; ++r) {
                int mrow = m0 + wr*64 + i*16 + lq*4 + r;
                size_t idx = (((size_t)b*NN + mrow)*(SPLITA*2) + sp*2 + wc)*2;
                part[idx] = rm[i][r]; part[idx+1] = rs[i][r];
            }
    }
}

// ---------------- combine split row stats (SPLITA*2 partials); store (rmax, 1/rsum) ----------------
__global__ __launch_bounds__(256) void pct_rowcomb(const float* __restrict__ part,
    float* __restrict__ rstat)
{
    int idx = blockIdx.x*256 + threadIdx.x;
    const float* p = part + (size_t)idx*(SPLITA*2)*2;
    float m = NEG_BIG;
    for (int s = 0; s < SPLITA*2; ++s) m = fmaxf(m, p[s*2]);
    float sum = 0.f;
    for (int s = 0; s < SPLITA*2; ++s) sum += p[s*2+1] * __expf(p[s*2] - m);
    rstat[idx*2] = m; rstat[idx*2+1] = 1.0f / sum;
}

// ---------------- pass B: column sums of softmax(Q@K^T) via MFMA ----------------
__global__ __launch_bounds__(256) void pct_colsum_mfma(
    const __hip_bfloat16* __restrict__ Q, const __hip_bfloat16* __restrict__ Kb,
    const float* __restrict__ rstat, float* __restrict__ S)
{
    __shared__ __align__(16) __hip_bfloat16 Asm[128*64];
    __shared__ __align__(16) __hip_bfloat16 Bsm[128*64];
    const int b = blockIdx.x, nt = blockIdx.y, sp = blockIdx.z;
    const int tid = threadIdx.x;
    const int lane = tid & 63, w = tid >> 6;
    const int ln = lane & 15, lq = lane >> 4;
    const int wr = w >> 1, wc = w & 1;
    const __hip_bfloat16* qb = Q + (size_t)b*NN*CC;
    const __hip_bfloat16* kb = Kb + (size_t)b*NN*CC;
    const float2* rst = (const float2*)rstat + (size_t)b*NN;
    const int n0 = nt*128;
    float cs[4] = {0.f,0.f,0.f,0.f};
    const int mbeg = sp*(NN/SPLITB);
    for (int m0 = mbeg; m0 < mbeg + NN/SPLITB; m0 += 128) {
        f32x4 acc[4][4];
        #pragma unroll
        for (int i = 0; i < 4; ++i)
            #pragma unroll
            for (int j = 0; j < 4; ++j) acc[i][j] = (f32x4){0.f,0.f,0.f,0.f};
        for (int c = 0; c < 4; ++c) {
            stage_chunk(qb, m0, c*64, Asm, tid);
            stage_chunk(kb, n0, c*64, Bsm, tid);
            __syncthreads();
            mfma_chunk(Asm, Bsm, wr, wc, ln, lq, acc);
            __syncthreads();
        }
        #pragma unroll
        for (int i = 0; i < 4; ++i)
            #pragma unroll
            for (int r = 0; r < 4; ++r) {
                int mrow = m0 + wr*64 + i*16 + lq*4 + r;
                float2 st = rst[mrow];
                #pragma unroll
                for (int j = 0; j < 4; ++j)
                    cs[j] += __expf(acc[i][j][r] - st.x) * st.y;
            }
    }
    #pragma unroll
    for (int j = 0; j < 4; ++j) {
        cs[j] += __shfl_xor(cs[j], 16, 64);
        cs[j] += __shfl_xor(cs[j], 32, 64);
    }
    if (lane < 16) {
        #pragma unroll
        for (int j = 0; j < 4; ++j)
            atomicAdd(&S[(size_t)b*NN + n0 + wc*64 + j*16 + ln], cs[j]);
    }
}

// ---------------- scale v rows by col = S/(eps+S) ----------------
__global__ __launch_bounds__(256) void pct_vscale(float* __restrict__ v, const float* __restrict__ S)
{
    int r = blockIdx.x, c = threadIdx.x;
    float s = S[r];
    float f = s / (1e-9f + s);
    v[(size_t)r*CC + c] *= f;
}

extern "C" void kernel_launch(void* const* d_in, const int* in_sizes, int n_in,
                              void* d_out, int out_size, void* d_ws, size_t ws_size,
                              hipStream_t stream)
{
    const float* inp  = (const float*)d_in[0];
    const float* w0   = (const float*)d_in[1];
    const float* b0   = (const float*)d_in[2];
    const float* ln0s = (const float*)d_in[3];
    const float* ln0b = (const float*)d_in[4];
    const float* w1   = (const float*)d_in[5];
    const float* b1   = (const float*)d_in[6];
    const float* ln1s = (const float*)d_in[7];
    const float* ln1b = (const float*)d_in[8];
    const float* wq   = (const float*)d_in[9];
    const float* bq   = (const float*)d_in[10];
    const float* wk   = (const float*)d_in[11];
    const float* bk   = (const float*)d_in[12];
    const float* wv   = (const float*)d_in[13];
    const float* bv   = (const float*)d_in[14];
    const float* wo   = (const float*)d_in[15];
    const float* bo   = (const float*)d_in[16];
    const float* alns = (const float*)d_in[17];
    const float* alnb = (const float*)d_in[18];
    const float* wf   = (const float*)d_in[19];
    const float* bfb  = (const float*)d_in[20];
    float* out = (float*)d_out;

    float* ws = (float*)d_ws;
    float* x1    = ws;                                   // RR*CC
    float* xcat  = x1 + (size_t)RR*CC;                   // RR*FF
    float* qb    = xcat + (size_t)RR*FF;                 // RR*CC
    float* kb    = qb + (size_t)RR*CC;                   // RR*CC
    float* vb    = kb + (size_t)RR*CC;                   // RR*CC
    float* part  = vb + (size_t)RR*CC;                   // RR*SPLITA*2*2
    float* rstat = part + (size_t)RR*SPLITA*2*2;         // RR*2
    float* Ssum  = rstat + (size_t)RR*2;                 // RR
    float* lns   = Ssum + RR;                            // BB*CC*2
    __hip_bfloat16* qh = (__hip_bfloat16*)(lns + BB*CC*2);   // RR*CC bf16
    __hip_bfloat16* kh = qh + (size_t)RR*CC;                 // RR*CC bf16

    dim3 blk(256);

    // pre-conv stack
    pct_embed<<<RR, blk, 0, stream>>>(inp, w0, b0, kb);
    hipMemsetAsync(lns, 0, BB*CC*2*sizeof(float), stream);
    pct_colstat<<<dim3(BB,64), blk, 0, stream>>>(kb, CC, lns);
    pct_lnapply<<<RR, blk, 0, stream>>>(kb, CC, lns, ln0s, ln0b, nullptr, 0, vb, CC, 0);
    pct_gemm<<<dim3(RR/64, CC/64), blk, 0, stream>>>(vb, CC, w1, CC, b1, qb, CC, CC);
    hipMemsetAsync(lns, 0, BB*CC*2*sizeof(float), stream);
    pct_colstat<<<dim3(BB,64), blk, 0, stream>>>(qb, CC, lns);
    pct_lnapply<<<RR, blk, 0, stream>>>(qb, CC, lns, ln1s, ln1b, nullptr, 0, x1, CC, 0);

    const float* xin = x1; int ldx = CC;
    for (int i = 0; i < NLAYER; ++i) {
        const float* wqi = wq + (size_t)i*CC*CC; const float* bqi = bq + i*CC;
        const float* wki = wk + (size_t)i*CC*CC; const float* bki = bk + i*CC;
        const float* wvi = wv + (size_t)i*CC*CC; const float* bvi = bv + i*CC;
        const float* woi = wo + (size_t)i*CC*CC; const float* boi = bo + i*CC;

        pct_gemm<<<dim3(RR/64, CC/64), blk, 0, stream>>>(xin, ldx, wqi, CC, bqi, qb, CC, CC);
        pct_gemm<<<dim3(RR/64, CC/64), blk, 0, stream>>>(xin, ldx, wki, CC, bki, kb, CC, CC);
        pct_gemm<<<dim3(RR/64, CC/64), blk, 0, stream>>>(xin, ldx, wvi, CC, bvi, vb, CC, CC);

        pct_tobf16<<<RR*CC/1024, blk, 0, stream>>>(qb, qh);
        pct_tobf16<<<RR*CC/1024, blk, 0, stream>>>(kb, kh);

        pct_rowstats_mfma<<<dim3(BB, NN/128, SPLITA), blk, 0, stream>>>(qh, kh, part);
        pct_rowcomb<<<RR/256, blk, 0, stream>>>(part, rstat);
        hipMemsetAsync(Ssum, 0, RR*sizeof(float), stream);
        pct_colsum_mfma<<<dim3(BB, NN/128, SPLITB), blk, 0, stream>>>(qh, kh, rstat, Ssum);

        pct_vscale<<<RR, blk, 0, stream>>>(vb, Ssum);
        pct_gemm<<<dim3(RR/64, CC/64), blk, 0, stream>>>(vb, CC, woi, CC, boi, qb, CC, CC);

        hipMemsetAsync(lns, 0, BB*CC*2*sizeof(float), stream);
        pct_colstat<<<dim3(BB,64), blk, 0, stream>>>(qb, CC, lns);
        pct_lnapply<<<RR, blk, 0, stream>>>(qb, CC, lns, alns + i*CC, alnb + i*CC,
                                            xin, ldx, xcat + i*CC, FF, 1);
        xin = xcat + i*CC; ldx = FF;
    }

    pct_gemm<<<dim3(RR/64, FF/64), blk, 0, stream>>>(xcat, FF, wf, FF, bfb, out, FF, FF);
}

// Round 4
// 710.900 us; speedup vs baseline: 4.1743x; 1.6607x over previous
//
#include <hip/hip_runtime.h>

#define BB 2
#define NN 4096
#define CC 256
#define FF 1024
#define NLAYER 4
#define RR (BB*NN)
#define SPLITA 8
#define SPLITB 8
#define NEG_BIG (-1e30f)

typedef _Float16 h16;
typedef __attribute__((ext_vector_type(8))) _Float16 half8;
typedef __attribute__((ext_vector_type(4))) float f32x4;

// ---------------- async global->LDS, 16B per lane ----------------
__device__ __forceinline__ void gload16(const h16* g, h16* l) {
    __builtin_amdgcn_global_load_lds((const __attribute__((address_space(1))) void*)g,
                                     (__attribute__((address_space(3))) void*)l, 16, 0, 0);
}

// stage ROWS x 64 h16 chunk (rows row0.., k-cols c0..c0+63, row stride ld)
// into lds[ROWS][64] with piece-XOR swizzle (phys piece pp holds logical pp^(row&7))
template<int ROWS>
__device__ __forceinline__ void stage_rows(const h16* __restrict__ src, int ld,
    int row0, int c0, h16* lds, int tid)
{
    int w = tid >> 6;
    #pragma unroll
    for (int t = 0; t < ROWS/32; ++t) {
        int slot = t*256 + tid;
        int row = slot >> 3;
        int pp  = slot & 7;
        int piece = pp ^ (row & 7);
        gload16(src + (size_t)(row0 + row)*ld + c0 + piece*8,
                lds + (t*256 + w*64)*8);
    }
}

// read 8 contiguous h16 (logical k-piece pl) of LDS row
__device__ __forceinline__ half8 frag_ld(const h16* lds, int row, int pl) {
    return *(const half8*)(lds + row*64 + ((pl ^ (row & 7))*8));
}

// one K=64 chunk of a 128x128 MFMA tile: 2 k-steps x 4x4 16x16x32 MFMAs/wave
__device__ __forceinline__ void mfma_chunk(const h16* Asm, const h16* Bsm,
    int wr, int wc, int ln, int lq, f32x4 acc[4][4])
{
    #pragma unroll
    for (int kk = 0; kk < 2; ++kk) {
        half8 af[4], bfr[4];
        #pragma unroll
        for (int i = 0; i < 4; ++i) af[i] = frag_ld(Asm, wr*64 + i*16 + ln, kk*4 + lq);
        #pragma unroll
        for (int j = 0; j < 4; ++j) bfr[j] = frag_ld(Bsm, wc*64 + j*16 + ln, kk*4 + lq);
        #pragma unroll
        for (int i = 0; i < 4; ++i)
            #pragma unroll
            for (int j = 0; j < 4; ++j)
                acc[i][j] = __builtin_amdgcn_mfma_f32_16x16x32_f16(af[i], bfr[j], acc[i][j], 0, 0, 0);
    }
}

// ---------------- weight transpose+convert: W[K,N] f32 -> WT[N,K] f16 ----------------
__global__ __launch_bounds__(256) void pct_wtrans(const float* __restrict__ W,
    h16* __restrict__ WT, int K, int N)
{
    __shared__ h16 t[32][33];
    const float* Wl = W + (size_t)blockIdx.z*K*N;
    h16* WTl = WT + (size_t)blockIdx.z*K*N;
    int k0 = blockIdx.x*32, n0 = blockIdx.y*32;
    int tx = threadIdx.x & 31, ty = threadIdx.x >> 5;
    #pragma unroll
    for (int i = ty; i < 32; i += 8)
        t[i][tx] = (h16)Wl[(size_t)(k0+i)*N + n0 + tx];
    __syncthreads();
    #pragma unroll
    for (int i = ty; i < 32; i += 8)
        WTl[(size_t)(n0+i)*K + k0 + tx] = t[tx][i];
}

// ---------------- embed: [B,N,3] @ [3,256] + b -> f16 ----------------
__global__ __launch_bounds__(256) void pct_embed(const float* __restrict__ inp,
    const float* __restrict__ w0, const float* __restrict__ b0, h16* __restrict__ out)
{
    int r = blockIdx.x, c = threadIdx.x;
    float a0 = inp[r*3+0], a1 = inp[r*3+1], a2 = inp[r*3+2];
    out[(size_t)r*CC + c] = (h16)(b0[c] + a0*w0[c] + a1*w0[CC+c] + a2*w0[2*CC+c]);
}

// ---------------- column stats over points axis (f16 in, f32 sums) ----------------
__global__ __launch_bounds__(256) void pct_colstat(const h16* __restrict__ x, int ldx,
    float* __restrict__ sums)
{
    int b = blockIdx.x, blk = blockIdx.y;
    const int rows = NN / 64;
    int c = threadIdx.x;
    const h16* p = x + ((size_t)b*NN + (size_t)blk*rows)*ldx + c;
    float s1 = 0.f, s2 = 0.f;
    for (int i = 0; i < rows; ++i) { float v = (float)p[(size_t)i*ldx]; s1 += v; s2 += v*v; }
    atomicAdd(&sums[(b*CC + c)*2 + 0], s1);
    atomicAdd(&sums[(b*CC + c)*2 + 1], s2);
}

// ---------------- apply LN (stats over points), optional relu + residual (f16) ----------------
__global__ __launch_bounds__(256) void pct_lnapply(const h16* __restrict__ x, int ldx,
    const float* __restrict__ sums, const float* __restrict__ scale, const float* __restrict__ bias,
    const h16* __restrict__ res, int ldr, h16* __restrict__ out, int ldo,
    int do_relu)
{
    int r = blockIdx.x, c = threadIdx.x;
    int b = r / NN;
    float s1 = sums[(b*CC + c)*2], s2 = sums[(b*CC + c)*2 + 1];
    float mu  = s1 * (1.f/NN);
    float var = s2 * (1.f/NN) - mu*mu;
    float rstd = rsqrtf(var + 1e-6f);
    float y = ((float)x[(size_t)r*ldx + c] - mu) * rstd * scale[c] + bias[c];
    if (do_relu) y = fmaxf(y, 0.f);
    if (res) y += (float)res[(size_t)r*ldr + c];
    out[(size_t)r*ldo + c] = (h16)y;
}

// ---------------- f16 MFMA GEMM (NT): out[m,n] = bias[n] + sum_k A[m,k]*WT[n,k] ----------------
template<int BN, bool OUT_F32>
__global__ __launch_bounds__(256) void pct_gemm_f16(
    const h16* __restrict__ A, int lda,
    const h16* __restrict__ WT, const float* __restrict__ bias,
    void* __restrict__ outp, int ldo, int K)
{
    constexpr int BJ = BN/2;      // cols per wave-col
    constexpr int NF = BJ/16;     // B frags per wave
    __shared__ __align__(16) h16 Asm[128*64];
    __shared__ __align__(16) h16 Bsm[BN*64];
    const int tid = threadIdx.x;
    const int lane = tid & 63, w = tid >> 6;
    const int ln = lane & 15, lq = lane >> 4;
    const int wr = w >> 1, wc = w & 1;
    const int m0 = blockIdx.x*128, n0 = blockIdx.y*BN;
    f32x4 acc[4][NF];
    #pragma unroll
    for (int i = 0; i < 4; ++i)
        #pragma unroll
        for (int j = 0; j < NF; ++j) acc[i][j] = (f32x4){0.f,0.f,0.f,0.f};
    for (int k0 = 0; k0 < K; k0 += 64) {
        stage_rows<128>(A, lda, m0, k0, Asm, tid);
        stage_rows<BN>(WT, K, n0, k0, Bsm, tid);
        __syncthreads();
        #pragma unroll
        for (int kk = 0; kk < 2; ++kk) {
            half8 af[4], bfr[NF];
            #pragma unroll
            for (int i = 0; i < 4; ++i) af[i] = frag_ld(Asm, wr*64 + i*16 + ln, kk*4 + lq);
            #pragma unroll
            for (int j = 0; j < NF; ++j) bfr[j] = frag_ld(Bsm, wc*BJ + j*16 + ln, kk*4 + lq);
            #pragma unroll
            for (int i = 0; i < 4; ++i)
                #pragma unroll
                for (int j = 0; j < NF; ++j)
                    acc[i][j] = __builtin_amdgcn_mfma_f32_16x16x32_f16(af[i], bfr[j], acc[i][j], 0, 0, 0);
        }
        __syncthreads();
    }
    #pragma unroll
    for (int j = 0; j < NF; ++j) {
        int col = n0 + wc*BJ + j*16 + ln;
        float bv = bias[col];
        #pragma unroll
        for (int i = 0; i < 4; ++i) {
            #pragma unroll
            for (int r = 0; r < 4; ++r) {
                int row = m0 + wr*64 + i*16 + lq*4 + r;
                float v = acc[i][j][r] + bv;
                if (OUT_F32) ((float*)outp)[(size_t)row*ldo + col] = v;
                else ((h16*)outp)[(size_t)row*ldo + col] = (h16)v;
            }
        }
    }
}

// ---------------- pass A: row max/sumexp of Q@K^T via MFMA ----------------
__global__ __launch_bounds__(256) void pct_rowstats_mfma(
    const h16* __restrict__ Q, const h16* __restrict__ Kb,
    float* __restrict__ part)
{
    __shared__ __align__(16) h16 Asm[128*64];
    __shared__ __align__(16) h16 Bsm[128*64];
    const int b = blockIdx.x, mt = blockIdx.y, sp = blockIdx.z;
    const int tid = threadIdx.x;
    const int lane = tid & 63, w = tid >> 6;
    const int ln = lane & 15, lq = lane >> 4;
    const int wr = w >> 1, wc = w & 1;
    const h16* qb = Q + (size_t)b*NN*CC;
    const h16* kb = Kb + (size_t)b*NN*CC;
    const int m0 = mt*128;
    float rm[4][4], rs[4][4];
    #pragma unroll
    for (int i = 0; i < 4; ++i)
        #pragma unroll
        for (int r = 0; r < 4; ++r) { rm[i][r] = NEG_BIG; rs[i][r] = 0.f; }

    const int nbeg = sp*(NN/SPLITA);
    for (int n0 = nbeg; n0 < nbeg + NN/SPLITA; n0 += 128) {
        f32x4 acc[4][4];
        #pragma unroll
        for (int i = 0; i < 4; ++i)
            #pragma unroll
            for (int j = 0; j < 4; ++j) acc[i][j] = (f32x4){0.f,0.f,0.f,0.f};
        for (int c = 0; c < 4; ++c) {
            stage_rows<128>(qb, CC, m0, c*64, Asm, tid);
            stage_rows<128>(kb, CC, n0, c*64, Bsm, tid);
            __syncthreads();
            mfma_chunk(Asm, Bsm, wr, wc, ln, lq, acc);
            __syncthreads();
        }
        #pragma unroll
        for (int i = 0; i < 4; ++i)
            #pragma unroll
            for (int r = 0; r < 4; ++r) {
                float a0 = acc[i][0][r], a1 = acc[i][1][r], a2 = acc[i][2][r], a3 = acc[i][3][r];
                float tm = fmaxf(fmaxf(a0,a1), fmaxf(a2,a3));
                float m = rm[i][r];
                if (tm > m) { rs[i][r] *= __expf(m - tm); m = tm; rm[i][r] = tm; }
                rs[i][r] += __expf(a0-m) + __expf(a1-m) + __expf(a2-m) + __expf(a3-m);
            }
    }
    #pragma unroll
    for (int i = 0; i < 4; ++i)
        #pragma unroll
        for (int r = 0; r < 4; ++r) {
            float m = rm[i][r], s = rs[i][r];
            #pragma unroll
            for (int msk = 1; msk <= 8; msk <<= 1) {
                float mo = __shfl_xor(m, msk, 64);
                float so = __shfl_xor(s, msk, 64);
                float mn = fmaxf(m, mo);
                s = s*__expf(m-mn) + so*__expf(mo-mn);
                m = mn;
            }
            rm[i][r] = m; rs[i][r] = s;
        }
    if (ln == 0) {
        #pragma unroll
        for (int i = 0; i < 4; ++i)
            #pragma unroll
            for (int r = 0; r < 4; ++r) {
                int mrow = m0 + wr*64 + i*16 + lq*4 + r;
                size_t idx = (((size_t)b*NN + mrow)*(SPLITA*2) + sp*2 + wc)*2;
                part[idx] = rm[i][r]; part[idx+1] = rs[i][r];
            }
    }
}

// ---------------- combine split row stats; store (rmax, 1/rsum) ----------------
__global__ __launch_bounds__(256) void pct_rowcomb(const float* __restrict__ part,
    float* __restrict__ rstat)
{
    int idx = blockIdx.x*256 + threadIdx.x;
    const float* p = part + (size_t)idx*(SPLITA*2)*2;
    float m = NEG_BIG;
    for (int s = 0; s < SPLITA*2; ++s) m = fmaxf(m, p[s*2]);
    float sum = 0.f;
    for (int s = 0; s < SPLITA*2; ++s) sum += p[s*2+1] * __expf(p[s*2] - m);
    rstat[idx*2] = m; rstat[idx*2+1] = 1.0f / sum;
}

// ---------------- pass B: column sums of softmax(Q@K^T) via MFMA ----------------
__global__ __launch_bounds__(256) void pct_colsum_mfma(
    const h16* __restrict__ Q, const h16* __restrict__ Kb,
    const float* __restrict__ rstat, float* __restrict__ S)
{
    __shared__ __align__(16) h16 Asm[128*64];
    __shared__ __align__(16) h16 Bsm[128*64];
    const int b = blockIdx.x, nt = blockIdx.y, sp = blockIdx.z;
    const int tid = threadIdx.x;
    const int lane = tid & 63, w = tid >> 6;
    const int ln = lane & 15, lq = lane >> 4;
    const int wr = w >> 1, wc = w & 1;
    const h16* qb = Q + (size_t)b*NN*CC;
    const h16* kb = Kb + (size_t)b*NN*CC;
    const float2* rst = (const float2*)rstat + (size_t)b*NN;
    const int n0 = nt*128;
    float cs[4] = {0.f,0.f,0.f,0.f};
    const int mbeg = sp*(NN/SPLITB);
    for (int m0 = mbeg; m0 < mbeg + NN/SPLITB; m0 += 128) {
        f32x4 acc[4][4];
        #pragma unroll
        for (int i = 0; i < 4; ++i)
            #pragma unroll
            for (int j = 0; j < 4; ++j) acc[i][j] = (f32x4){0.f,0.f,0.f,0.f};
        for (int c = 0; c < 4; ++c) {
            stage_rows<128>(qb, CC, m0, c*64, Asm, tid);
            stage_rows<128>(kb, CC, n0, c*64, Bsm, tid);
            __syncthreads();
            mfma_chunk(Asm, Bsm, wr, wc, ln, lq, acc);
            __syncthreads();
        }
        #pragma unroll
        for (int i = 0; i < 4; ++i)
            #pragma unroll
            for (int r = 0; r < 4; ++r) {
                int mrow = m0 + wr*64 + i*16 + lq*4 + r;
                float2 st = rst[mrow];
                #pragma unroll
                for (int j = 0; j < 4; ++j)
                    cs[j] += __expf(acc[i][j][r] - st.x) * st.y;
            }
    }
    #pragma unroll
    for (int j = 0; j < 4; ++j) {
        cs[j] += __shfl_xor(cs[j], 16, 64);
        cs[j] += __shfl_xor(cs[j], 32, 64);
    }
    if (lane < 16) {
        #pragma unroll
        for (int j = 0; j < 4; ++j)
            atomicAdd(&S[(size_t)b*NN + n0 + wc*64 + j*16 + ln], cs[j]);
    }
}

// ---------------- scale v rows by col = S/(eps+S) (f16) ----------------
__global__ __launch_bounds__(256) void pct_vscale(h16* __restrict__ v,
    const float* __restrict__ S)
{
    int r = blockIdx.x, c = threadIdx.x;
    float s = S[r];
    float f = s / (1e-9f + s);
    v[(size_t)r*CC + c] = (h16)((float)v[(size_t)r*CC + c] * f);
}

extern "C" void kernel_launch(void* const* d_in, const int* in_sizes, int n_in,
                              void* d_out, int out_size, void* d_ws, size_t ws_size,
                              hipStream_t stream)
{
    const float* inp  = (const float*)d_in[0];
    const float* w0   = (const float*)d_in[1];
    const float* b0   = (const float*)d_in[2];
    const float* ln0s = (const float*)d_in[3];
    const float* ln0b = (const float*)d_in[4];
    const float* w1   = (const float*)d_in[5];
    const float* b1   = (const float*)d_in[6];
    const float* ln1s = (const float*)d_in[7];
    const float* ln1b = (const float*)d_in[8];
    const float* wq   = (const float*)d_in[9];
    const float* bq   = (const float*)d_in[10];
    const float* wk   = (const float*)d_in[11];
    const float* bk   = (const float*)d_in[12];
    const float* wv   = (const float*)d_in[13];
    const float* bv   = (const float*)d_in[14];
    const float* wo   = (const float*)d_in[15];
    const float* bo   = (const float*)d_in[16];
    const float* alns = (const float*)d_in[17];
    const float* alnb = (const float*)d_in[18];
    const float* wf   = (const float*)d_in[19];
    const float* bfb  = (const float*)d_in[20];
    float* out = (float*)d_out;

    // workspace layout
    char* p = (char*)d_ws;
    auto alloc = [&](size_t bytes) { char* r = p; p += (bytes + 255) & ~255ULL; return r; };
    h16* t0   = (h16*)alloc((size_t)RR*CC*2);
    h16* t1   = (h16*)alloc((size_t)RR*CC*2);
    h16* t2   = (h16*)alloc((size_t)RR*CC*2);
    h16* x1   = (h16*)alloc((size_t)RR*CC*2);
    h16* qh   = (h16*)alloc((size_t)RR*CC*2);
    h16* kh   = (h16*)alloc((size_t)RR*CC*2);
    h16* vh   = (h16*)alloc((size_t)RR*CC*2);
    h16* oh   = (h16*)alloc((size_t)RR*CC*2);
    h16* xcat = (h16*)alloc((size_t)RR*FF*2);
    h16* w1T  = (h16*)alloc((size_t)CC*CC*2);
    h16* wqT  = (h16*)alloc((size_t)NLAYER*CC*CC*2);
    h16* wkT  = (h16*)alloc((size_t)NLAYER*CC*CC*2);
    h16* wvT  = (h16*)alloc((size_t)NLAYER*CC*CC*2);
    h16* woT  = (h16*)alloc((size_t)NLAYER*CC*CC*2);
    h16* wfT  = (h16*)alloc((size_t)FF*FF*2);
    float* part  = (float*)alloc((size_t)RR*(SPLITA*2)*2*4);
    float* rstat = (float*)alloc((size_t)RR*2*4);
    float* Ssum  = (float*)alloc((size_t)NLAYER*RR*4);   // zeroed below
    float* lns   = (float*)alloc((size_t)6*BB*CC*2*4);   // zeroed below (adjacent)

    dim3 blk(256);

    // zero Ssum..lns span in one memset (adjacent in layout)
    hipMemsetAsync(Ssum, 0, (size_t)((char*)(lns + 6*BB*CC*2) - (char*)Ssum), stream);

    // weight transpose+convert
    pct_wtrans<<<dim3(CC/32, CC/32, 1), blk, 0, stream>>>(w1, w1T, CC, CC);
    pct_wtrans<<<dim3(CC/32, CC/32, NLAYER), blk, 0, stream>>>(wq, wqT, CC, CC);
    pct_wtrans<<<dim3(CC/32, CC/32, NLAYER), blk, 0, stream>>>(wk, wkT, CC, CC);
    pct_wtrans<<<dim3(CC/32, CC/32, NLAYER), blk, 0, stream>>>(wv, wvT, CC, CC);
    pct_wtrans<<<dim3(CC/32, CC/32, NLAYER), blk, 0, stream>>>(wo, woT, CC, CC);
    pct_wtrans<<<dim3(FF/32, FF/32, 1), blk, 0, stream>>>(wf, wfT, FF, FF);

    // pre-conv stack
    pct_embed<<<RR, blk, 0, stream>>>(inp, w0, b0, t0);
    pct_colstat<<<dim3(BB,64), blk, 0, stream>>>(t0, CC, lns + 0*BB*CC*2);
    pct_lnapply<<<RR, blk, 0, stream>>>(t0, CC, lns + 0*BB*CC*2, ln0s, ln0b, nullptr, 0, t1, CC, 0);
    pct_gemm_f16<64,false><<<dim3(RR/128, CC/64), blk, 0, stream>>>(t1, CC, w1T, b1, t2, CC, CC);
    pct_colstat<<<dim3(BB,64), blk, 0, stream>>>(t2, CC, lns + 1*BB*CC*2);
    pct_lnapply<<<RR, blk, 0, stream>>>(t2, CC, lns + 1*BB*CC*2, ln1s, ln1b, nullptr, 0, x1, CC, 0);

    const h16* xin = x1; int ldx = CC;
    for (int i = 0; i < NLAYER; ++i) {
        pct_gemm_f16<64,false><<<dim3(RR/128, CC/64), blk, 0, stream>>>(xin, ldx, wqT + (size_t)i*CC*CC, bq + i*CC, qh, CC, CC);
        pct_gemm_f16<64,false><<<dim3(RR/128, CC/64), blk, 0, stream>>>(xin, ldx, wkT + (size_t)i*CC*CC, bk + i*CC, kh, CC, CC);
        pct_gemm_f16<64,false><<<dim3(RR/128, CC/64), blk, 0, stream>>>(xin, ldx, wvT + (size_t)i*CC*CC, bv + i*CC, vh, CC, CC);

        pct_rowstats_mfma<<<dim3(BB, NN/128, SPLITA), blk, 0, stream>>>(qh, kh, part);
        pct_rowcomb<<<RR/256, blk, 0, stream>>>(part, rstat);
        pct_colsum_mfma<<<dim3(BB, NN/128, SPLITB), blk, 0, stream>>>(qh, kh, rstat, Ssum + (size_t)i*RR);

        pct_vscale<<<RR, blk, 0, stream>>>(vh, Ssum + (size_t)i*RR);
        pct_gemm_f16<64,false><<<dim3(RR/128, CC/64), blk, 0, stream>>>(vh, CC, woT + (size_t)i*CC*CC, bo + i*CC, oh, CC, CC);

        pct_colstat<<<dim3(BB,64), blk, 0, stream>>>(oh, CC, lns + (2+i)*BB*CC*2);
        pct_lnapply<<<RR, blk, 0, stream>>>(oh, CC, lns + (2+i)*BB*CC*2, alns + i*CC, alnb + i*CC,
                                            xin, ldx, xcat + i*CC, FF, 1);
        xin = xcat + i*CC; ldx = FF;
    }

    pct_gemm_f16<128,true><<<dim3(RR/128, FF/128), blk, 0, stream>>>(xcat, FF, wfT, bfb, out, FF, FF);
}

// Round 5
// 676.165 us; speedup vs baseline: 4.3888x; 1.0514x over previous
//
#include <hip/hip_runtime.h>

#define BB 2
#define NN 4096
#define CC 256
#define FF 1024
#define NLAYER 4
#define RR (BB*NN)
#define SPLITA 4
#define SPLITB 4
#define QKLD (3*CC)      // qkv packed row stride = 768
#define NEG_BIG (-1e30f)

typedef _Float16 h16;
typedef __attribute__((ext_vector_type(8))) _Float16 half8;
typedef __attribute__((ext_vector_type(4))) float f32x4;

// ---------------- async global->LDS, 16B per lane ----------------
__device__ __forceinline__ void gload16(const h16* g, h16* l) {
    __builtin_amdgcn_global_load_lds((const __attribute__((address_space(1))) void*)g,
                                     (__attribute__((address_space(3))) void*)l, 16, 0, 0);
}

// stage ROWS x 64 h16 chunk (rows row0.., k-cols c0..c0+63, row stride ld)
// into lds[ROWS][64] with piece-XOR swizzle (phys piece pp holds logical pp^(row&7))
template<int ROWS>
__device__ __forceinline__ void stage_rows(const h16* __restrict__ src, int ld,
    int row0, int c0, h16* lds, int tid)
{
    int w = tid >> 6;
    #pragma unroll
    for (int t = 0; t < ROWS/32; ++t) {
        int slot = t*256 + tid;
        int row = slot >> 3;
        int pp  = slot & 7;
        int piece = pp ^ (row & 7);
        gload16(src + (size_t)(row0 + row)*ld + c0 + piece*8,
                lds + (t*256 + w*64)*8);
    }
}

// read 8 contiguous h16 (logical k-piece pl) of LDS row
__device__ __forceinline__ half8 frag_ld(const h16* lds, int row, int pl) {
    return *(const half8*)(lds + row*64 + ((pl ^ (row & 7))*8));
}

// ---------------- weight transpose+convert: W[K,N] f32 -> WT[N,K] f16 ----------------
__global__ __launch_bounds__(256) void pct_wtrans(const float* __restrict__ W,
    h16* __restrict__ WT, int K, int N, int dstride)
{
    __shared__ h16 t[32][33];
    const float* Wl = W + (size_t)blockIdx.z*K*N;
    h16* WTl = WT + (size_t)blockIdx.z*dstride;
    int k0 = blockIdx.x*32, n0 = blockIdx.y*32;
    int tx = threadIdx.x & 31, ty = threadIdx.x >> 5;
    #pragma unroll
    for (int i = ty; i < 32; i += 8)
        t[i][tx] = (h16)Wl[(size_t)(k0+i)*N + n0 + tx];
    __syncthreads();
    #pragma unroll
    for (int i = ty; i < 32; i += 8)
        WTl[(size_t)(n0+i)*K + k0 + tx] = t[tx][i];
}

// ---------------- pack q/k/v biases into [NLAYER][768] ----------------
__global__ __launch_bounds__(256) void pct_bias3(const float* __restrict__ bq,
    const float* __restrict__ bk, const float* __restrict__ bv, float* __restrict__ o)
{
    int l = blockIdx.x, c = threadIdx.x;
    o[l*QKLD + c]        = bq[l*CC + c];
    o[l*QKLD + CC + c]   = bk[l*CC + c];
    o[l*QKLD + 2*CC + c] = bv[l*CC + c];
}

// ---------------- embed: [B,N,3] @ [3,256] + b -> f16 ----------------
__global__ __launch_bounds__(256) void pct_embed(const float* __restrict__ inp,
    const float* __restrict__ w0, const float* __restrict__ b0, h16* __restrict__ out)
{
    int r = blockIdx.x, c = threadIdx.x;
    float a0 = inp[r*3+0], a1 = inp[r*3+1], a2 = inp[r*3+2];
    out[(size_t)r*CC + c] = (h16)(b0[c] + a0*w0[c] + a1*w0[CC+c] + a2*w0[2*CC+c]);
}

// ---------------- column stats over points axis (f16 in, f32 sums) ----------------
__global__ __launch_bounds__(256) void pct_colstat(const h16* __restrict__ x, int ldx,
    float* __restrict__ sums)
{
    int b = blockIdx.x, blk = blockIdx.y;
    const int rows = NN / 64;
    int c = threadIdx.x;
    const h16* p = x + ((size_t)b*NN + (size_t)blk*rows)*ldx + c;
    float s1 = 0.f, s2 = 0.f;
    for (int i = 0; i < rows; ++i) { float v = (float)p[(size_t)i*ldx]; s1 += v; s2 += v*v; }
    atomicAdd(&sums[(b*CC + c)*2 + 0], s1);
    atomicAdd(&sums[(b*CC + c)*2 + 1], s2);
}

// ---------------- apply LN (stats over points), optional relu + residual (f16) ----------------
__global__ __launch_bounds__(256) void pct_lnapply(const h16* __restrict__ x, int ldx,
    const float* __restrict__ sums, const float* __restrict__ scale, const float* __restrict__ bias,
    const h16* __restrict__ res, int ldr, h16* __restrict__ out, int ldo,
    int do_relu)
{
    int r = blockIdx.x, c = threadIdx.x;
    int b = r / NN;
    float s1 = sums[(b*CC + c)*2], s2 = sums[(b*CC + c)*2 + 1];
    float mu  = s1 * (1.f/NN);
    float var = s2 * (1.f/NN) - mu*mu;
    float rstd = rsqrtf(var + 1e-6f);
    float y = ((float)x[(size_t)r*ldx + c] - mu) * rstd * scale[c] + bias[c];
    if (do_relu) y = fmaxf(y, 0.f);
    if (res) y += (float)res[(size_t)r*ldr + c];
    out[(size_t)r*ldo + c] = (h16)y;
}

// ---------------- f16 MFMA GEMM (NT): out[m,n] = rowS(m)*(sum_k A[m,k]*WT[n,k]) + bias[n] ----------------
template<int BN, bool OUT_F32>
__global__ __launch_bounds__(256) void pct_gemm_f16(
    const h16* __restrict__ A, int lda,
    const h16* __restrict__ WT, const float* __restrict__ bias,
    void* __restrict__ outp, int ldo, int K, const float* __restrict__ rowS)
{
    constexpr int BJ = BN/2;      // cols per wave-col
    constexpr int NF = BJ/16;     // B frags per wave
    __shared__ __align__(16) h16 Asm[128*64];
    __shared__ __align__(16) h16 Bsm[BN*64];
    const int tid = threadIdx.x;
    const int lane = tid & 63, w = tid >> 6;
    const int ln = lane & 15, lq = lane >> 4;
    const int wr = w >> 1, wc = w & 1;
    const int m0 = blockIdx.x*128, n0 = blockIdx.y*BN;
    f32x4 acc[4][NF];
    #pragma unroll
    for (int i = 0; i < 4; ++i)
        #pragma unroll
        for (int j = 0; j < NF; ++j) acc[i][j] = (f32x4){0.f,0.f,0.f,0.f};
    for (int k0 = 0; k0 < K; k0 += 64) {
        stage_rows<128>(A, lda, m0, k0, Asm, tid);
        stage_rows<BN>(WT, K, n0, k0, Bsm, tid);
        __syncthreads();
        #pragma unroll
        for (int kk = 0; kk < 2; ++kk) {
            half8 af[4], bfr[NF];
            #pragma unroll
            for (int i = 0; i < 4; ++i) af[i] = frag_ld(Asm, wr*64 + i*16 + ln, kk*4 + lq);
            #pragma unroll
            for (int j = 0; j < NF; ++j) bfr[j] = frag_ld(Bsm, wc*BJ + j*16 + ln, kk*4 + lq);
            #pragma unroll
            for (int i = 0; i < 4; ++i)
                #pragma unroll
                for (int j = 0; j < NF; ++j)
                    acc[i][j] = __builtin_amdgcn_mfma_f32_16x16x32_f16(af[i], bfr[j], acc[i][j], 0, 0, 0);
        }
        __syncthreads();
    }
    #pragma unroll
    for (int j = 0; j < NF; ++j) {
        int col = n0 + wc*BJ + j*16 + ln;
        float bv = bias[col];
        #pragma unroll
        for (int i = 0; i < 4; ++i) {
            #pragma unroll
            for (int r = 0; r < 4; ++r) {
                int row = m0 + wr*64 + i*16 + lq*4 + r;
                float sc = 1.f;
                if (rowS) { float s = rowS[row]; sc = s / (1e-9f + s); }
                float v = acc[i][j][r] * sc + bv;
                if (OUT_F32) ((float*)outp)[(size_t)row*ldo + col] = v;
                else ((h16*)outp)[(size_t)row*ldo + col] = (h16)v;
            }
        }
    }
}

// ---------------- pass A: row max/sumexp of Q@K^T.  Q-tile (64 x 256) LDS-resident;
// K streamed in 256-row tiles, 64-k chunks. Wave w covers n-cols w*64..w*64+63. ----------------
__global__ __launch_bounds__(256) void pct_rowstats2(const h16* __restrict__ QKV,
    float* __restrict__ part)
{
    __shared__ __align__(16) h16 Qs[4*4096];   // 32 KB: 4 chunks of 64x64
    __shared__ __align__(16) h16 Ks[16384];    // 32 KB: 256x64 streamed chunk
    const int b = blockIdx.x, mt = blockIdx.y, sp = blockIdx.z;
    const int tid = threadIdx.x;
    const int lane = tid & 63, w = tid >> 6;
    const int ln = lane & 15, lq = lane >> 4;
    const h16* qb = QKV + (size_t)b*NN*QKLD;
    const h16* kb = QKV + (size_t)b*NN*QKLD + CC;
    const int m0 = mt*64;
    #pragma unroll
    for (int c = 0; c < 4; ++c)
        stage_rows<64>(qb, QKLD, m0, c*64, Qs + c*4096, tid);
    float rm[4][4], rs[4][4];
    #pragma unroll
    for (int i = 0; i < 4; ++i)
        #pragma unroll
        for (int r = 0; r < 4; ++r) { rm[i][r] = NEG_BIG; rs[i][r] = 0.f; }

    const int nbeg = sp*(NN/SPLITA);
    for (int n0 = nbeg; n0 < nbeg + NN/SPLITA; n0 += 256) {
        f32x4 acc[4][4];
        #pragma unroll
        for (int i = 0; i < 4; ++i)
            #pragma unroll
            for (int j = 0; j < 4; ++j) acc[i][j] = (f32x4){0.f,0.f,0.f,0.f};
        #pragma unroll
        for (int c = 0; c < 4; ++c) {
            stage_rows<256>(kb, QKLD, n0, c*64, Ks, tid);
            __syncthreads();          // K chunk ready (also drains Q stage on first pass)
            #pragma unroll
            for (int kk = 0; kk < 2; ++kk) {
                half8 af[4], bfr[4];
                #pragma unroll
                for (int i = 0; i < 4; ++i) af[i] = frag_ld(Qs + c*4096, i*16 + ln, kk*4 + lq);
                #pragma unroll
                for (int j = 0; j < 4; ++j) bfr[j] = frag_ld(Ks, w*64 + j*16 + ln, kk*4 + lq);
                #pragma unroll
                for (int i = 0; i < 4; ++i)
                    #pragma unroll
                    for (int j = 0; j < 4; ++j)
                        acc[i][j] = __builtin_amdgcn_mfma_f32_16x16x32_f16(af[i], bfr[j], acc[i][j], 0, 0, 0);
            }
            __syncthreads();          // all waves done with Ks before restage
        }
        #pragma unroll
        for (int i = 0; i < 4; ++i)
            #pragma unroll
            for (int r = 0; r < 4; ++r) {
                float a0 = acc[i][0][r], a1 = acc[i][1][r], a2 = acc[i][2][r], a3 = acc[i][3][r];
                float tm = fmaxf(fmaxf(a0,a1), fmaxf(a2,a3));
                float m = rm[i][r];
                if (tm > m) { rs[i][r] *= __expf(m - tm); m = tm; rm[i][r] = tm; }
                rs[i][r] += __expf(a0-m) + __expf(a1-m) + __expf(a2-m) + __expf(a3-m);
            }
    }
    // combine 16 n-lanes within wave; wave w is one of 4 partials per row
    #pragma unroll
    for (int i = 0; i < 4; ++i)
        #pragma unroll
        for (int r = 0; r < 4; ++r) {
            float m = rm[i][r], s = rs[i][r];
            #pragma unroll
            for (int msk = 1; msk <= 8; msk <<= 1) {
                float mo = __shfl_xor(m, msk, 64);
                float so = __shfl_xor(s, msk, 64);
                float mn = fmaxf(m, mo);
                s = s*__expf(m-mn) + so*__expf(mo-mn);
                m = mn;
            }
            rm[i][r] = m; rs[i][r] = s;
        }
    if (ln == 0) {
        #pragma unroll
        for (int i = 0; i < 4; ++i)
            #pragma unroll
            for (int r = 0; r < 4; ++r) {
                int mrow = m0 + i*16 + lq*4 + r;
                size_t idx = (((size_t)b*NN + mrow)*(SPLITA*4) + sp*4 + w)*2;
                part[idx] = rm[i][r]; part[idx+1] = rs[i][r];
            }
    }
}

// ---------------- combine 16 split row stats; store (rmax, 1/rsum) ----------------
__global__ __launch_bounds__(256) void pct_rowcomb(const float* __restrict__ part,
    float* __restrict__ rstat)
{
    int idx = blockIdx.x*256 + threadIdx.x;
    const float* p = part + (size_t)idx*(SPLITA*4)*2;
    float m = NEG_BIG;
    for (int s = 0; s < SPLITA*4; ++s) m = fmaxf(m, p[s*2]);
    float sum = 0.f;
    for (int s = 0; s < SPLITA*4; ++s) sum += p[s*2+1] * __expf(p[s*2] - m);
    rstat[idx*2] = m; rstat[idx*2+1] = 1.0f / sum;
}

// ---------------- pass B: column sums of softmax.  K-tile (64 x 256) LDS-resident;
// Q streamed in 256-row tiles. Wave w covers m-rows w*64..w*64+63. ----------------
__global__ __launch_bounds__(256) void pct_colsum2(const h16* __restrict__ QKV,
    const float* __restrict__ rstat, float* __restrict__ S)
{
    __shared__ __align__(16) h16 Ks4[4*4096];  // 32 KB resident K tile (64 n-rows x K256)
    __shared__ __align__(16) h16 Qc[16384];    // 32 KB streamed Q chunk (256 x 64)
    const int b = blockIdx.x, nt = blockIdx.y, sp = blockIdx.z;
    const int tid = threadIdx.x;
    const int lane = tid & 63, w = tid >> 6;
    const int ln = lane & 15, lq = lane >> 4;
    const h16* qb = QKV + (size_t)b*NN*QKLD;
    const h16* kb = QKV + (size_t)b*NN*QKLD + CC;
    const int n0 = nt*64;
    #pragma unroll
    for (int c = 0; c < 4; ++c)
        stage_rows<64>(kb, QKLD, n0, c*64, Ks4 + c*4096, tid);
    const float2* rst = (const float2*)rstat + (size_t)b*NN;
    float cs[4] = {0.f,0.f,0.f,0.f};
    const int mbeg = sp*(NN/SPLITB);
    for (int m0 = mbeg; m0 < mbeg + NN/SPLITB; m0 += 256) {
        f32x4 acc[4][4];
        #pragma unroll
        for (int i = 0; i < 4; ++i)
            #pragma unroll
            for (int j = 0; j < 4; ++j) acc[i][j] = (f32x4){0.f,0.f,0.f,0.f};
        #pragma unroll
        for (int c = 0; c < 4; ++c) {
            stage_rows<256>(qb, QKLD, m0, c*64, Qc, tid);
            __syncthreads();
            #pragma unroll
            for (int kk = 0; kk < 2; ++kk) {
                half8 af[4], bfr[4];
                #pragma unroll
                for (int i = 0; i < 4; ++i) af[i] = frag_ld(Qc, w*64 + i*16 + ln, kk*4 + lq);
                #pragma unroll
                for (int j = 0; j < 4; ++j) bfr[j] = frag_ld(Ks4 + c*4096, j*16 + ln, kk*4 + lq);
                #pragma unroll
                for (int i = 0; i < 4; ++i)
                    #pragma unroll
                    for (int j = 0; j < 4; ++j)
                        acc[i][j] = __builtin_amdgcn_mfma_f32_16x16x32_f16(af[i], bfr[j], acc[i][j], 0, 0, 0);
            }
            __syncthreads();
        }
        #pragma unroll
        for (int i = 0; i < 4; ++i)
            #pragma unroll
            for (int r = 0; r < 4; ++r) {
                int mrow = m0 + w*64 + i*16 + lq*4 + r;
                float2 st = rst[mrow];
                #pragma unroll
                for (int j = 0; j < 4; ++j)
                    cs[j] += __expf(acc[i][j][r] - st.x) * st.y;
            }
    }
    #pragma unroll
    for (int j = 0; j < 4; ++j) {
        cs[j] += __shfl_xor(cs[j], 16, 64);
        cs[j] += __shfl_xor(cs[j], 32, 64);
    }
    if (lane < 16) {
        #pragma unroll
        for (int j = 0; j < 4; ++j)
            atomicAdd(&S[(size_t)b*NN + n0 + j*16 + ln], cs[j]);
    }
}

extern "C" void kernel_launch(void* const* d_in, const int* in_sizes, int n_in,
                              void* d_out, int out_size, void* d_ws, size_t ws_size,
                              hipStream_t stream)
{
    const float* inp  = (const float*)d_in[0];
    const float* w0   = (const float*)d_in[1];
    const float* b0   = (const float*)d_in[2];
    const float* ln0s = (const float*)d_in[3];
    const float* ln0b = (const float*)d_in[4];
    const float* w1   = (const float*)d_in[5];
    const float* b1   = (const float*)d_in[6];
    const float* ln1s = (const float*)d_in[7];
    const float* ln1b = (const float*)d_in[8];
    const float* wq   = (const float*)d_in[9];
    const float* bq   = (const float*)d_in[10];
    const float* wk   = (const float*)d_in[11];
    const float* bk   = (const float*)d_in[12];
    const float* wv   = (const float*)d_in[13];
    const float* bv   = (const float*)d_in[14];
    const float* wo   = (const float*)d_in[15];
    const float* bo   = (const float*)d_in[16];
    const float* alns = (const float*)d_in[17];
    const float* alnb = (const float*)d_in[18];
    const float* wf   = (const float*)d_in[19];
    const float* bfb  = (const float*)d_in[20];
    float* out = (float*)d_out;

    // workspace layout
    char* p = (char*)d_ws;
    auto alloc = [&](size_t bytes) { char* r = p; p += (bytes + 255) & ~255ULL; return r; };
    h16* t0    = (h16*)alloc((size_t)RR*CC*2);
    h16* t1    = (h16*)alloc((size_t)RR*CC*2);
    h16* t2    = (h16*)alloc((size_t)RR*CC*2);
    h16* x1    = (h16*)alloc((size_t)RR*CC*2);
    h16* qkv   = (h16*)alloc((size_t)RR*QKLD*2);
    h16* oh    = (h16*)alloc((size_t)RR*CC*2);
    h16* xcat  = (h16*)alloc((size_t)RR*FF*2);
    h16* w1T   = (h16*)alloc((size_t)CC*CC*2);
    h16* wqkvT = (h16*)alloc((size_t)NLAYER*QKLD*CC*2);
    h16* woT   = (h16*)alloc((size_t)NLAYER*CC*CC*2);
    h16* wfT   = (h16*)alloc((size_t)FF*FF*2);
    float* bqkv  = (float*)alloc((size_t)NLAYER*QKLD*4);
    float* part  = (float*)alloc((size_t)RR*(SPLITA*4)*2*4);
    float* rstat = (float*)alloc((size_t)RR*2*4);
    float* Ssum  = (float*)alloc((size_t)NLAYER*RR*4);   // zeroed below
    float* lns   = (float*)alloc((size_t)6*BB*CC*2*4);   // zeroed below (adjacent)

    dim3 blk(256);

    // zero Ssum..lns span in one memset (adjacent in layout)
    hipMemsetAsync(Ssum, 0, (size_t)((char*)(lns + 6*BB*CC*2) - (char*)Ssum), stream);

    // weight transpose+convert (+pack q/k/v)
    pct_wtrans<<<dim3(CC/32, CC/32, 1), blk, 0, stream>>>(w1, w1T, CC, CC, CC*CC);
    pct_wtrans<<<dim3(CC/32, CC/32, NLAYER), blk, 0, stream>>>(wq, wqkvT,            CC, CC, QKLD*CC);
    pct_wtrans<<<dim3(CC/32, CC/32, NLAYER), blk, 0, stream>>>(wk, wqkvT + CC*CC,    CC, CC, QKLD*CC);
    pct_wtrans<<<dim3(CC/32, CC/32, NLAYER), blk, 0, stream>>>(wv, wqkvT + 2*CC*CC,  CC, CC, QKLD*CC);
    pct_wtrans<<<dim3(CC/32, CC/32, NLAYER), blk, 0, stream>>>(wo, woT, CC, CC, CC*CC);
    pct_wtrans<<<dim3(FF/32, FF/32, 1), blk, 0, stream>>>(wf, wfT, FF, FF, FF*FF);
    pct_bias3<<<NLAYER, blk, 0, stream>>>(bq, bk, bv, bqkv);

    // pre-conv stack
    pct_embed<<<RR, blk, 0, stream>>>(inp, w0, b0, t0);
    pct_colstat<<<dim3(BB,64), blk, 0, stream>>>(t0, CC, lns + 0*BB*CC*2);
    pct_lnapply<<<RR, blk, 0, stream>>>(t0, CC, lns + 0*BB*CC*2, ln0s, ln0b, nullptr, 0, t1, CC, 0);
    pct_gemm_f16<64,false><<<dim3(RR/128, CC/64), blk, 0, stream>>>(t1, CC, w1T, b1, t2, CC, CC, nullptr);
    pct_colstat<<<dim3(BB,64), blk, 0, stream>>>(t2, CC, lns + 1*BB*CC*2);
    pct_lnapply<<<RR, blk, 0, stream>>>(t2, CC, lns + 1*BB*CC*2, ln1s, ln1b, nullptr, 0, x1, CC, 0);

    const h16* xin = x1; int ldx = CC;
    for (int i = 0; i < NLAYER; ++i) {
        // fused q/k/v GEMM -> qkv[RR][768]
        pct_gemm_f16<64,false><<<dim3(RR/128, QKLD/64), blk, 0, stream>>>(
            xin, ldx, wqkvT + (size_t)i*QKLD*CC, bqkv + i*QKLD, qkv, QKLD, CC, nullptr);

        pct_rowstats2<<<dim3(BB, NN/64, SPLITA), blk, 0, stream>>>(qkv, part);
        pct_rowcomb<<<RR/256, blk, 0, stream>>>(part, rstat);
        pct_colsum2<<<dim3(BB, NN/64, SPLITB), blk, 0, stream>>>(qkv, rstat, Ssum + (size_t)i*RR);

        // wo GEMM on v (rows scaled by col[m] in epilogue)
        pct_gemm_f16<64,false><<<dim3(RR/128, CC/64), blk, 0, stream>>>(
            qkv + 2*CC, QKLD, woT + (size_t)i*CC*CC, bo + i*CC, oh, CC, CC, Ssum + (size_t)i*RR);

        pct_colstat<<<dim3(BB,64), blk, 0, stream>>>(oh, CC, lns + (2+i)*BB*CC*2);
        pct_lnapply<<<RR, blk, 0, stream>>>(oh, CC, lns + (2+i)*BB*CC*2, alns + i*CC, alnb + i*CC,
                                            xin, ldx, xcat + i*CC, FF, 1);
        xin = xcat + i*CC; ldx = FF;
    }

    pct_gemm_f16<128,true><<<dim3(RR/128, FF/128), blk, 0, stream>>>(xcat, FF, wfT, bfb, out, FF, FF, nullptr);
}

// Round 6
// 612.161 us; speedup vs baseline: 4.8476x; 1.1046x over previous
//
#include <hip/hip_runtime.h>

#define BB 2
#define NN 4096
#define CC 256
#define FF 1024
#define NLAYER 4
#define RR (BB*NN)
#define SPLIT 16         // n/m split for attention passes
#define PSP 16           // row-stat partials per row
#define QKLD (3*CC)      // qkv packed row stride = 768
#define NEG_BIG (-1e30f)

typedef _Float16 h16;
typedef __attribute__((ext_vector_type(8))) _Float16 half8;
typedef __attribute__((ext_vector_type(4))) float f32x4;
typedef __attribute__((ext_vector_type(16))) float f32x16;

// ---------------- async global->LDS, 16B per lane ----------------
__device__ __forceinline__ void gload16(const h16* g, h16* l) {
    __builtin_amdgcn_global_load_lds((const __attribute__((address_space(1))) void*)g,
                                     (__attribute__((address_space(3))) void*)l, 16, 0, 0);
}

// stage ROWS x 64 h16 chunk (rows row0.., k-cols c0..c0+63, row stride ld)
// into lds[ROWS][64] with piece-XOR swizzle (phys piece pp holds logical pp^(row&7))
template<int ROWS>
__device__ __forceinline__ void stage_rows(const h16* __restrict__ src, int ld,
    int row0, int c0, h16* lds, int tid)
{
    int w = tid >> 6;
    #pragma unroll
    for (int t = 0; t < ROWS/32; ++t) {
        int slot = t*256 + tid;
        int row = slot >> 3;
        int pp  = slot & 7;
        int piece = pp ^ (row & 7);
        gload16(src + (size_t)(row0 + row)*ld + c0 + piece*8,
                lds + (t*256 + w*64)*8);
    }
}

// read 8 contiguous h16 (logical k-piece pl) of LDS row
__device__ __forceinline__ half8 frag_ld(const h16* lds, int row, int pl) {
    return *(const half8*)(lds + row*64 + ((pl ^ (row & 7))*8));
}

// ---------------- weight transpose+convert: W[K,N] f32 -> WT[N,K] f16 ----------------
__global__ __launch_bounds__(256) void pct_wtrans(const float* __restrict__ W,
    h16* __restrict__ WT, int K, int N, int dstride)
{
    __shared__ h16 t[32][33];
    const float* Wl = W + (size_t)blockIdx.z*K*N;
    h16* WTl = WT + (size_t)blockIdx.z*dstride;
    int k0 = blockIdx.x*32, n0 = blockIdx.y*32;
    int tx = threadIdx.x & 31, ty = threadIdx.x >> 5;
    #pragma unroll
    for (int i = ty; i < 32; i += 8)
        t[i][tx] = (h16)Wl[(size_t)(k0+i)*N + n0 + tx];
    __syncthreads();
    #pragma unroll
    for (int i = ty; i < 32; i += 8)
        WTl[(size_t)(n0+i)*K + k0 + tx] = t[tx][i];
}

// ---------------- pack q/k/v biases into [NLAYER][768] ----------------
__global__ __launch_bounds__(256) void pct_bias3(const float* __restrict__ bq,
    const float* __restrict__ bk, const float* __restrict__ bv, float* __restrict__ o)
{
    int l = blockIdx.x, c = threadIdx.x;
    o[l*QKLD + c]        = bq[l*CC + c];
    o[l*QKLD + CC + c]   = bk[l*CC + c];
    o[l*QKLD + 2*CC + c] = bv[l*CC + c];
}

// ---------------- embed: [B,N,3] @ [3,256] + b -> f16 ----------------
__global__ __launch_bounds__(256) void pct_embed(const float* __restrict__ inp,
    const float* __restrict__ w0, const float* __restrict__ b0, h16* __restrict__ out)
{
    int r = blockIdx.x, c = threadIdx.x;
    float a0 = inp[r*3+0], a1 = inp[r*3+1], a2 = inp[r*3+2];
    out[(size_t)r*CC + c] = (h16)(b0[c] + a0*w0[c] + a1*w0[CC+c] + a2*w0[2*CC+c]);
}

// ---------------- column stats over points axis (f16 in, f32 sums) ----------------
__global__ __launch_bounds__(256) void pct_colstat(const h16* __restrict__ x, int ldx,
    float* __restrict__ sums)
{
    int b = blockIdx.x, blk = blockIdx.y;
    const int rows = NN / 64;
    int c = threadIdx.x;
    const h16* p = x + ((size_t)b*NN + (size_t)blk*rows)*ldx + c;
    float s1 = 0.f, s2 = 0.f;
    for (int i = 0; i < rows; ++i) { float v = (float)p[(size_t)i*ldx]; s1 += v; s2 += v*v; }
    atomicAdd(&sums[(b*CC + c)*2 + 0], s1);
    atomicAdd(&sums[(b*CC + c)*2 + 1], s2);
}

// ---------------- apply LN (stats over points), optional relu + residual (f16) ----------------
__global__ __launch_bounds__(256) void pct_lnapply(const h16* __restrict__ x, int ldx,
    const float* __restrict__ sums, const float* __restrict__ scale, const float* __restrict__ bias,
    const h16* __restrict__ res, int ldr, h16* __restrict__ out, int ldo,
    int do_relu)
{
    int r = blockIdx.x, c = threadIdx.x;
    int b = r / NN;
    float s1 = sums[(b*CC + c)*2], s2 = sums[(b*CC + c)*2 + 1];
    float mu  = s1 * (1.f/NN);
    float var = s2 * (1.f/NN) - mu*mu;
    float rstd = rsqrtf(var + 1e-6f);
    float y = ((float)x[(size_t)r*ldx + c] - mu) * rstd * scale[c] + bias[c];
    if (do_relu) y = fmaxf(y, 0.f);
    if (res) y += (float)res[(size_t)r*ldr + c];
    out[(size_t)r*ldo + c] = (h16)y;
}

// ---------------- f16 MFMA GEMM (NT): out[m,n] = rowS(m)*(sum_k A[m,k]*WT[n,k]) + bias[n] ----------------
template<int BN, bool OUT_F32>
__global__ __launch_bounds__(256) void pct_gemm_f16(
    const h16* __restrict__ A, int lda,
    const h16* __restrict__ WT, const float* __restrict__ bias,
    void* __restrict__ outp, int ldo, int K, const float* __restrict__ rowS)
{
    constexpr int BJ = BN/2;      // cols per wave-col
    constexpr int NF = BJ/16;     // B frags per wave
    __shared__ __align__(16) h16 Asm[128*64];
    __shared__ __align__(16) h16 Bsm[BN*64];
    const int tid = threadIdx.x;
    const int lane = tid & 63, w = tid >> 6;
    const int ln = lane & 15, lq = lane >> 4;
    const int wr = w >> 1, wc = w & 1;
    const int m0 = blockIdx.x*128, n0 = blockIdx.y*BN;
    f32x4 acc[4][NF];
    #pragma unroll
    for (int i = 0; i < 4; ++i)
        #pragma unroll
        for (int j = 0; j < NF; ++j) acc[i][j] = (f32x4){0.f,0.f,0.f,0.f};
    for (int k0 = 0; k0 < K; k0 += 64) {
        stage_rows<128>(A, lda, m0, k0, Asm, tid);
        stage_rows<BN>(WT, K, n0, k0, Bsm, tid);
        __syncthreads();
        #pragma unroll
        for (int kk = 0; kk < 2; ++kk) {
            half8 af[4], bfr[NF];
            #pragma unroll
            for (int i = 0; i < 4; ++i) af[i] = frag_ld(Asm, wr*64 + i*16 + ln, kk*4 + lq);
            #pragma unroll
            for (int j = 0; j < NF; ++j) bfr[j] = frag_ld(Bsm, wc*BJ + j*16 + ln, kk*4 + lq);
            #pragma unroll
            for (int i = 0; i < 4; ++i)
                #pragma unroll
                for (int j = 0; j < NF; ++j)
                    acc[i][j] = __builtin_amdgcn_mfma_f32_16x16x32_f16(af[i], bfr[j], acc[i][j], 0, 0, 0);
        }
        __syncthreads();
    }
    #pragma unroll
    for (int j = 0; j < NF; ++j) {
        int col = n0 + wc*BJ + j*16 + ln;
        float bv = bias[col];
        #pragma unroll
        for (int i = 0; i < 4; ++i) {
            #pragma unroll
            for (int r = 0; r < 4; ++r) {
                int row = m0 + wr*64 + i*16 + lq*4 + r;
                float sc = 1.f;
                if (rowS) { float s = rowS[row]; sc = s / (1e-9f + s); }
                float v = acc[i][j][r] * sc + bv;
                if (OUT_F32) ((float*)outp)[(size_t)row*ldo + col] = v;
                else ((h16*)outp)[(size_t)row*ldo + col] = (h16)v;
            }
        }
    }
}

// ---------------- pass A: row max/sumexp of Q@K^T, 32x32x16 MFMA ----------------
// block: 128 m-rows x (NN/SPLIT n-range), 4 waves, wave = 32-row strip x 128 cols.
__global__ __launch_bounds__(256) void attn_rowstats(const h16* __restrict__ QKV,
    float2* __restrict__ part)
{
    __shared__ __align__(16) h16 Asm[128*64];
    __shared__ __align__(16) h16 Bsm[128*64];
    const int b = blockIdx.x, mt = blockIdx.y, sp = blockIdx.z;
    const int tid = threadIdx.x;
    const int lane = tid & 63, wr = tid >> 6;
    const int ln2 = lane & 31, h = lane >> 5;
    const h16* qb = QKV + (size_t)b*NN*QKLD;
    const h16* kb = qb + CC;
    const int m0 = mt*128;
    float rm[16], rs[16];
    #pragma unroll
    for (int g = 0; g < 16; ++g) { rm[g] = NEG_BIG; rs[g] = 0.f; }

    const int nbeg = sp*(NN/SPLIT);
    for (int n0 = nbeg; n0 < nbeg + NN/SPLIT; n0 += 128) {
        f32x16 acc[4];
        #pragma unroll
        for (int j = 0; j < 4; ++j) acc[j] = (f32x16)(0.f);
        #pragma unroll
        for (int c = 0; c < 4; ++c) {
            stage_rows<128>(qb, QKLD, m0, c*64, Asm, tid);
            stage_rows<128>(kb, QKLD, n0, c*64, Bsm, tid);
            __syncthreads();
            #pragma unroll
            for (int kk = 0; kk < 4; ++kk) {
                half8 af = frag_ld(Asm, wr*32 + ln2, kk*2 + h);
                #pragma unroll
                for (int j = 0; j < 4; ++j) {
                    half8 bf = frag_ld(Bsm, j*32 + ln2, kk*2 + h);
                    acc[j] = __builtin_amdgcn_mfma_f32_32x32x16_f16(af, bf, acc[j], 0, 0, 0);
                }
            }
            __syncthreads();
        }
        // online row stats: per g (fixed row), 4 cols (j)
        #pragma unroll
        for (int g = 0; g < 16; ++g) {
            float a0 = acc[0][g], a1 = acc[1][g], a2 = acc[2][g], a3 = acc[3][g];
            float tm = fmaxf(fmaxf(a0,a1), fmaxf(a2,a3));
            float m = rm[g];
            if (tm > m) { rs[g] *= __expf(m - tm); m = tm; rm[g] = tm; }
            rs[g] += __expf(a0-m) + __expf(a1-m) + __expf(a2-m) + __expf(a3-m);
        }
    }
    // reduce across the 32 col-lanes (rows differ only by h, which xor<=16 preserves)
    #pragma unroll
    for (int g = 0; g < 16; ++g) {
        float m = rm[g], s = rs[g];
        #pragma unroll
        for (int msk = 1; msk <= 16; msk <<= 1) {
            float mo = __shfl_xor(m, msk, 64);
            float so = __shfl_xor(s, msk, 64);
            float mn = fmaxf(m, mo);
            s = s*__expf(m-mn) + so*__expf(mo-mn);
            m = mn;
        }
        if (ln2 == 0) {
            int row = m0 + wr*32 + (g & 3) + 8*(g >> 2) + 4*h;
            part[((size_t)b*NN + row)*PSP + sp] = make_float2(m, s);
        }
    }
}

// ---------------- combine PSP split row stats; store (rmax, 1/rsum) ----------------
__global__ __launch_bounds__(256) void pct_rowcomb(const float2* __restrict__ part,
    float2* __restrict__ rstat)
{
    int idx = blockIdx.x*256 + threadIdx.x;
    const float2* p = part + (size_t)idx*PSP;
    float m = NEG_BIG;
    #pragma unroll
    for (int s = 0; s < PSP; ++s) m = fmaxf(m, p[s].x);
    float sum = 0.f;
    #pragma unroll
    for (int s = 0; s < PSP; ++s) sum += p[s].y * __expf(p[s].x - m);
    rstat[idx] = make_float2(m, 1.0f / sum);
}

// ---------------- pass B: column sums of softmax, 32x32x16 MFMA ----------------
// block: 128 n-rows (K side) x (NN/SPLIT m-range); acc = S^T tile; wave = 32-n strip x 128 m.
__global__ __launch_bounds__(256) void attn_colsums(const h16* __restrict__ QKV,
    const float2* __restrict__ rstat, float* __restrict__ S)
{
    __shared__ __align__(16) h16 Asm[128*64];   // K rows (resident role)
    __shared__ __align__(16) h16 Bsm[128*64];   // Q rows (streamed)
    const int b = blockIdx.x, nt = blockIdx.y, sp = blockIdx.z;
    const int tid = threadIdx.x;
    const int lane = tid & 63, wr = tid >> 6;
    const int ln2 = lane & 31, h = lane >> 5;
    const h16* qb = QKV + (size_t)b*NN*QKLD;
    const h16* kb = qb + CC;
    const float2* rst = rstat + (size_t)b*NN;
    const int n0 = nt*128;
    float cs[16];
    #pragma unroll
    for (int g = 0; g < 16; ++g) cs[g] = 0.f;

    const int mbeg = sp*(NN/SPLIT);
    for (int m0 = mbeg; m0 < mbeg + NN/SPLIT; m0 += 128) {
        f32x16 acc[4];
        #pragma unroll
        for (int j = 0; j < 4; ++j) acc[j] = (f32x16)(0.f);
        #pragma unroll
        for (int c = 0; c < 4; ++c) {
            stage_rows<128>(kb, QKLD, n0, c*64, Asm, tid);
            stage_rows<128>(qb, QKLD, m0, c*64, Bsm, tid);
            __syncthreads();
            #pragma unroll
            for (int kk = 0; kk < 4; ++kk) {
                half8 af = frag_ld(Asm, wr*32 + ln2, kk*2 + h);
                #pragma unroll
                for (int j = 0; j < 4; ++j) {
                    half8 bf = frag_ld(Bsm, j*32 + ln2, kk*2 + h);
                    acc[j] = __builtin_amdgcn_mfma_f32_32x32x16_f16(af, bf, acc[j], 0, 0, 0);
                }
            }
            __syncthreads();
        }
        // acc[j][g]: row n = n0+wr*32+rowfn(g,h), col m = m0+j*32+ln2
        #pragma unroll
        for (int j = 0; j < 4; ++j) {
            float2 st = rst[m0 + j*32 + ln2];
            #pragma unroll
            for (int g = 0; g < 16; ++g)
                cs[g] += __expf(acc[j][g] - st.x) * st.y;
        }
    }
    #pragma unroll
    for (int g = 0; g < 16; ++g) {
        float s = cs[g];
        #pragma unroll
        for (int msk = 1; msk <= 16; msk <<= 1)
            s += __shfl_xor(s, msk, 64);
        if (ln2 == 0) {
            int row = n0 + wr*32 + (g & 3) + 8*(g >> 2) + 4*h;
            atomicAdd(&S[(size_t)b*NN + row], s);
        }
    }
}

extern "C" void kernel_launch(void* const* d_in, const int* in_sizes, int n_in,
                              void* d_out, int out_size, void* d_ws, size_t ws_size,
                              hipStream_t stream)
{
    const float* inp  = (const float*)d_in[0];
    const float* w0   = (const float*)d_in[1];
    const float* b0   = (const float*)d_in[2];
    const float* ln0s = (const float*)d_in[3];
    const float* ln0b = (const float*)d_in[4];
    const float* w1   = (const float*)d_in[5];
    const float* b1   = (const float*)d_in[6];
    const float* ln1s = (const float*)d_in[7];
    const float* ln1b = (const float*)d_in[8];
    const float* wq   = (const float*)d_in[9];
    const float* bq   = (const float*)d_in[10];
    const float* wk   = (const float*)d_in[11];
    const float* bk   = (const float*)d_in[12];
    const float* wv   = (const float*)d_in[13];
    const float* bv   = (const float*)d_in[14];
    const float* wo   = (const float*)d_in[15];
    const float* bo   = (const float*)d_in[16];
    const float* alns = (const float*)d_in[17];
    const float* alnb = (const float*)d_in[18];
    const float* wf   = (const float*)d_in[19];
    const float* bfb  = (const float*)d_in[20];
    float* out = (float*)d_out;

    // workspace layout
    char* p = (char*)d_ws;
    auto alloc = [&](size_t bytes) { char* r = p; p += (bytes + 255) & ~255ULL; return r; };
    h16* t0    = (h16*)alloc((size_t)RR*CC*2);
    h16* t1    = (h16*)alloc((size_t)RR*CC*2);
    h16* t2    = (h16*)alloc((size_t)RR*CC*2);
    h16* x1    = (h16*)alloc((size_t)RR*CC*2);
    h16* qkv   = (h16*)alloc((size_t)RR*QKLD*2);
    h16* oh    = (h16*)alloc((size_t)RR*CC*2);
    h16* xcat  = (h16*)alloc((size_t)RR*FF*2);
    h16* w1T   = (h16*)alloc((size_t)CC*CC*2);
    h16* wqkvT = (h16*)alloc((size_t)NLAYER*QKLD*CC*2);
    h16* woT   = (h16*)alloc((size_t)NLAYER*CC*CC*2);
    h16* wfT   = (h16*)alloc((size_t)FF*FF*2);
    float* bqkv  = (float*)alloc((size_t)NLAYER*QKLD*4);
    float2* part  = (float2*)alloc((size_t)RR*PSP*8);
    float2* rstat = (float2*)alloc((size_t)RR*8);
    float* Ssum  = (float*)alloc((size_t)NLAYER*RR*4);   // zeroed below
    float* lns   = (float*)alloc((size_t)6*BB*CC*2*4);   // zeroed below (adjacent)

    dim3 blk(256);

    // zero Ssum..lns span in one memset (adjacent in layout)
    hipMemsetAsync(Ssum, 0, (size_t)((char*)(lns + 6*BB*CC*2) - (char*)Ssum), stream);

    // weight transpose+convert (+pack q/k/v)
    pct_wtrans<<<dim3(CC/32, CC/32, 1), blk, 0, stream>>>(w1, w1T, CC, CC, CC*CC);
    pct_wtrans<<<dim3(CC/32, CC/32, NLAYER), blk, 0, stream>>>(wq, wqkvT,            CC, CC, QKLD*CC);
    pct_wtrans<<<dim3(CC/32, CC/32, NLAYER), blk, 0, stream>>>(wk, wqkvT + CC*CC,    CC, CC, QKLD*CC);
    pct_wtrans<<<dim3(CC/32, CC/32, NLAYER), blk, 0, stream>>>(wv, wqkvT + 2*CC*CC,  CC, CC, QKLD*CC);
    pct_wtrans<<<dim3(CC/32, CC/32, NLAYER), blk, 0, stream>>>(wo, woT, CC, CC, CC*CC);
    pct_wtrans<<<dim3(FF/32, FF/32, 1), blk, 0, stream>>>(wf, wfT, FF, FF, FF*FF);
    pct_bias3<<<NLAYER, blk, 0, stream>>>(bq, bk, bv, bqkv);

    // pre-conv stack
    pct_embed<<<RR, blk, 0, stream>>>(inp, w0, b0, t0);
    pct_colstat<<<dim3(BB,64), blk, 0, stream>>>(t0, CC, lns + 0*BB*CC*2);
    pct_lnapply<<<RR, blk, 0, stream>>>(t0, CC, lns + 0*BB*CC*2, ln0s, ln0b, nullptr, 0, t1, CC, 0);
    pct_gemm_f16<64,false><<<dim3(RR/128, CC/64), blk, 0, stream>>>(t1, CC, w1T, b1, t2, CC, CC, nullptr);
    pct_colstat<<<dim3(BB,64), blk, 0, stream>>>(t2, CC, lns + 1*BB*CC*2);
    pct_lnapply<<<RR, blk, 0, stream>>>(t2, CC, lns + 1*BB*CC*2, ln1s, ln1b, nullptr, 0, x1, CC, 0);

    const h16* xin = x1; int ldx = CC;
    for (int i = 0; i < NLAYER; ++i) {
        // fused q/k/v GEMM -> qkv[RR][768]
        pct_gemm_f16<64,false><<<dim3(RR/128, QKLD/64), blk, 0, stream>>>(
            xin, ldx, wqkvT + (size_t)i*QKLD*CC, bqkv + i*QKLD, qkv, QKLD, CC, nullptr);

        attn_rowstats<<<dim3(BB, NN/128, SPLIT), blk, 0, stream>>>(qkv, part);
        pct_rowcomb<<<RR/256, blk, 0, stream>>>(part, rstat);
        attn_colsums<<<dim3(BB, NN/128, SPLIT), blk, 0, stream>>>(qkv, rstat, Ssum + (size_t)i*RR);

        // wo GEMM on v (rows scaled by col[m] in epilogue)
        pct_gemm_f16<64,false><<<dim3(RR/128, CC/64), blk, 0, stream>>>(
            qkv + 2*CC, QKLD, woT + (size_t)i*CC*CC, bo + i*CC, oh, CC, CC, Ssum + (size_t)i*RR);

        pct_colstat<<<dim3(BB,64), blk, 0, stream>>>(oh, CC, lns + (2+i)*BB*CC*2);
        pct_lnapply<<<RR, blk, 0, stream>>>(oh, CC, lns + (2+i)*BB*CC*2, alns + i*CC, alnb + i*CC,
                                            xin, ldx, xcat + i*CC, FF, 1);
        xin = xcat + i*CC; ldx = FF;
    }

    pct_gemm_f16<128,true><<<dim3(RR/128, FF/128), blk, 0, stream>>>(xcat, FF, wfT, bfb, out, FF, FF, nullptr);
}